// Round 1
// baseline (161.077 us; speedup 1.0000x reference)
//
#include <hip/hip_runtime.h>
#include <stdint.h>

// Encoder: B=2,E=512,T=2048,H=8,dh=64, local window |i-j|<=64
// Pipeline: transpose/split x -> split-bf16 GEMM (qkv) -> local attention (MFMA)
//           -> split-bf16 GEMM (out proj) -> transpose*x+relu

#define DEVI __device__ __forceinline__

typedef __attribute__((ext_vector_type(8))) short bf16x8;   // 8 bf16 in 4 VGPRs
typedef __attribute__((ext_vector_type(4))) float f32x4;

DEVI unsigned short f2bf(float f) {               // RNE float->bf16
  unsigned u = __float_as_uint(f);
  u += 0x7fffu + ((u >> 16) & 1u);
  return (unsigned short)(u >> 16);
}
DEVI float bf2f(unsigned short h) { return __uint_as_float(((unsigned)h) << 16); }

#define GLL16(gp, lp)                                                          \
  __builtin_amdgcn_global_load_lds(                                            \
      (const __attribute__((address_space(1))) void*)(gp),                     \
      (__attribute__((address_space(3))) void*)(lp), 16, 0, 0)

#define MFMA(a, b, c) __builtin_amdgcn_mfma_f32_16x16x32_bf16((a), (b), (c), 0, 0, 0)

// ---------------------------------------------------------------------------
// K0a: x[B,E,T] fp32 -> xT[B*T, 512] split bf16 (hi/lo), LDS tile transpose
__global__ __launch_bounds__(256) void k_transpose_split_x(
    const float* __restrict__ x, unsigned short* __restrict__ xh,
    unsigned short* __restrict__ xl) {
  __shared__ float tile[32][33];
  const int b = blockIdx.z, e0 = blockIdx.y * 32, t0 = blockIdx.x * 32;
  const int j = threadIdx.x & 31, i = threadIdx.x >> 5;  // i: 0..7
#pragma unroll
  for (int rr = 0; rr < 4; rr++) {
    int e = e0 + i + rr * 8;
    tile[i + rr * 8][j] = x[((size_t)b * 512 + e) * 2048 + t0 + j];  // coalesced t
  }
  __syncthreads();
#pragma unroll
  for (int rr = 0; rr < 4; rr++) {
    int t = t0 + i + rr * 8;
    float v = tile[j][i + rr * 8];
    size_t o = ((size_t)b * 2048 + t) * 512 + e0 + j;  // coalesced e
    unsigned short hv = f2bf(v);
    xh[o] = hv;
    xl[o] = f2bf(v - bf2f(hv));
  }
}

// K0b: elementwise split-convert fp32 -> bf16 hi/lo
__global__ __launch_bounds__(256) void k_split_convert(
    const float* __restrict__ in, unsigned short* __restrict__ hi,
    unsigned short* __restrict__ lo, int n) {
  int i = blockIdx.x * 256 + threadIdx.x;
  if (i < n) {
    float v = in[i];
    unsigned short h = f2bf(v);
    hi[i] = h;
    lo[i] = f2bf(v - bf2f(h));
  }
}

// ---------------------------------------------------------------------------
// Split-bf16 GEMM: C[m,n] = sum_k A[m,k]*B[n,k] + bias[n]
// A = Ah+Al, B = Bh+Bl, 3 passes (hh, hl, lh). 128x128 tile, BK=32, 4 waves.
// mode 0: scatter into Q(*0.125)/K/V [B,H,T,64] bf16. mode 1: fp32 [M,512].
__global__ __launch_bounds__(256) void k_gemm_split(
    const unsigned short* __restrict__ Ahg, const unsigned short* __restrict__ Alg,
    const unsigned short* __restrict__ Bhg, const unsigned short* __restrict__ Blg,
    const float* __restrict__ bias, int mode,
    unsigned short* __restrict__ Qs, unsigned short* __restrict__ Kks,
    unsigned short* __restrict__ Vvs, float* __restrict__ attn_out) {
  const int KD = 512;
  __shared__ __align__(16) unsigned short Ah_s[128 * 32];
  __shared__ __align__(16) unsigned short Al_s[128 * 32];
  __shared__ __align__(16) unsigned short Bh_s[128 * 32];
  __shared__ __align__(16) unsigned short Bl_s[128 * 32];
  const int tid = threadIdx.x, lane = tid & 63, w = tid >> 6;
  const int m0 = blockIdx.y * 128, n0 = blockIdx.x * 128;
  const int wm = (w >> 1) * 64, wn = (w & 1) * 64;

  f32x4 acc[4][4];
#pragma unroll
  for (int i = 0; i < 4; i++)
#pragma unroll
    for (int j = 0; j < 4; j++) acc[i][j] = (f32x4){0.f, 0.f, 0.f, 0.f};

  // staging: per wave 2 calls/array; call covers 16 rows x 32 cols (1KB)
  const int sr = w * 32 + (lane >> 2);
  const int sc = (lane & 3) * 8;
  const size_t a0 = (size_t)(m0 + sr) * KD + sc;
  const size_t a1 = (size_t)(m0 + sr + 16) * KD + sc;
  const size_t b0 = (size_t)(n0 + sr) * KD + sc;
  const size_t b1 = (size_t)(n0 + sr + 16) * KD + sc;
  unsigned short* lA0 = &Ah_s[(w * 32) * 32];
  unsigned short* lA1 = &Ah_s[(w * 32 + 16) * 32];
  unsigned short* lAl0 = &Al_s[(w * 32) * 32];
  unsigned short* lAl1 = &Al_s[(w * 32 + 16) * 32];
  unsigned short* lB0 = &Bh_s[(w * 32) * 32];
  unsigned short* lB1 = &Bh_s[(w * 32 + 16) * 32];
  unsigned short* lBl0 = &Bl_s[(w * 32) * 32];
  unsigned short* lBl1 = &Bl_s[(w * 32 + 16) * 32];

  const int fm = lane & 15, fq = (lane >> 4) * 8;

  for (int k0 = 0; k0 < KD; k0 += 32) {
    __syncthreads();
    GLL16(Ahg + a0 + k0, lA0);
    GLL16(Ahg + a1 + k0, lA1);
    GLL16(Alg + a0 + k0, lAl0);
    GLL16(Alg + a1 + k0, lAl1);
    GLL16(Bhg + b0 + k0, lB0);
    GLL16(Bhg + b1 + k0, lB1);
    GLL16(Blg + b0 + k0, lBl0);
    GLL16(Blg + b1 + k0, lBl1);
    __builtin_amdgcn_s_waitcnt(0);
    __syncthreads();

    bf16x8 ah[4], al[4], bh[4], bl[4];
#pragma unroll
    for (int i = 0; i < 4; i++) {
      ah[i] = *(const bf16x8*)&Ah_s[(wm + i * 16 + fm) * 32 + fq];
      al[i] = *(const bf16x8*)&Al_s[(wm + i * 16 + fm) * 32 + fq];
      bh[i] = *(const bf16x8*)&Bh_s[(wn + i * 16 + fm) * 32 + fq];
      bl[i] = *(const bf16x8*)&Bl_s[(wn + i * 16 + fm) * 32 + fq];
    }
#pragma unroll
    for (int i = 0; i < 4; i++)
#pragma unroll
      for (int j = 0; j < 4; j++) {
        acc[i][j] = MFMA(ah[i], bh[j], acc[i][j]);
        acc[i][j] = MFMA(ah[i], bl[j], acc[i][j]);
        acc[i][j] = MFMA(al[i], bh[j], acc[i][j]);
      }
  }

  // epilogue: C/D layout col=lane&15, row=quad*4+r  [m89-verified]
  const int quad = lane >> 4;
#pragma unroll
  for (int i = 0; i < 4; i++)
#pragma unroll
    for (int j = 0; j < 4; j++) {
      int gn = n0 + wn + j * 16 + fm;
      float bv = bias[gn];
#pragma unroll
      for (int r = 0; r < 4; r++) {
        int gm = m0 + wm + i * 16 + quad * 4 + r;
        float v = acc[i][j][r] + bv;
        if (mode == 0) {
          int bb = gm >> 11, t = gm & 2047;
          int sec = gn >> 9, cc = gn & 511;
          int h = cc >> 6, d = cc & 63;
          if (sec == 0) v *= 0.125f;  // 1/sqrt(64), exact
          unsigned short* dst = sec == 0 ? Qs : (sec == 1 ? Kks : Vvs);
          dst[(((size_t)(bb * 8 + h)) * 2048 + t) * 64 + d] = f2bf(v);
        } else {
          attn_out[(size_t)gm * 512 + gn] = v;
        }
      }
    }
}

// ---------------------------------------------------------------------------
// K2: local attention. Block = (b,h, 64 queries). Window = 192 keys.
#define KSTR 88   // K_lds row stride (bf16): 176B, 2-way-free b128 reads
#define VSTR 216  // Vt/P row stride (bf16): 432B, 2-way-free b128 reads
__global__ __launch_bounds__(256) void k_attention(
    const unsigned short* __restrict__ Qs, const unsigned short* __restrict__ Kks,
    const unsigned short* __restrict__ Vvs, unsigned short* __restrict__ ctx_hi,
    unsigned short* __restrict__ ctx_lo) {
  __shared__ __align__(16) unsigned short KP_s[192 * KSTR];  // K, later P (64 x VSTR)
  __shared__ __align__(16) unsigned short Vt_s[64 * VSTR];   // V^T [dh][key]
  __shared__ float redm[4 * 64];
  __shared__ float reds[4 * 64];

  const int tid = threadIdx.x, lane = tid & 63, w = tid >> 6;
  const int q0 = blockIdx.x * 64;
  const int bh = blockIdx.y;
  const int j0 = q0 - 64;
  const size_t base = (size_t)bh * 2048 * 64;

  // stage K rows (clamped; garbage rows are masked before softmax)
  for (int idx = tid; idx < 192 * 8; idx += 256) {
    int r = idx >> 3, c = idx & 7;
    int j = j0 + r;
    j = j < 0 ? 0 : (j > 2047 ? 2047 : j);
    uint4 v = *(const uint4*)&Kks[base + (size_t)j * 64 + c * 8];
    *(uint4*)&KP_s[r * KSTR + c * 8] = v;
  }
  // stage V transposed; OOB rows ZERO (0*garbage hazard)
  for (int idx = tid; idx < 192 * 64; idx += 256) {
    int r = idx >> 6, d = idx & 63;
    int j = j0 + r;
    unsigned short v = (j >= 0 && j < 2048) ? Vvs[base + (size_t)j * 64 + d]
                                            : (unsigned short)0;
    Vt_s[d * VSTR + r] = v;
  }

  // Q fragments straight from global (A layout: m=lane&15, k=quad*8+j)
  const int fm = lane & 15, quad = lane >> 4;
  bf16x8 aq[4][2];
#pragma unroll
  for (int mt = 0; mt < 4; mt++)
#pragma unroll
    for (int ks = 0; ks < 2; ks++)
      aq[mt][ks] = *(const bf16x8*)&Qs[base + (size_t)(q0 + mt * 16 + fm) * 64 +
                                       ks * 32 + quad * 8];
  __syncthreads();

  // S = Qs @ K^T ; wave covers key-cols [w*48, w*48+48)
  const int n0s = w * 48;
  f32x4 s_acc[4][3];
#pragma unroll
  for (int mt = 0; mt < 4; mt++)
#pragma unroll
    for (int nt = 0; nt < 3; nt++) s_acc[mt][nt] = (f32x4){0.f, 0.f, 0.f, 0.f};
#pragma unroll
  for (int nt = 0; nt < 3; nt++)
#pragma unroll
    for (int ks = 0; ks < 2; ks++) {
      bf16x8 bk =
          *(const bf16x8*)&KP_s[(n0s + nt * 16 + fm) * KSTR + ks * 32 + quad * 8];
#pragma unroll
      for (int mt = 0; mt < 4; mt++) s_acc[mt][nt] = MFMA(aq[mt][ks], bk, s_acc[mt][nt]);
    }

  // mask (REPLACE, not add) + per-row max
  float rm[4][4];
#pragma unroll
  for (int mt = 0; mt < 4; mt++)
#pragma unroll
    for (int r = 0; r < 4; r++) rm[mt][r] = -1e30f;
#pragma unroll
  for (int mt = 0; mt < 4; mt++)
#pragma unroll
    for (int nt = 0; nt < 3; nt++) {
      int jj = n0s + nt * 16 + fm;
      int jg = j0 + jj;
#pragma unroll
      for (int r = 0; r < 4; r++) {
        int ii = mt * 16 + quad * 4 + r;
        bool ok = (jj >= ii) && (jj <= ii + 128) && (jg >= 0) && (jg < 2048);
        float sv = ok ? s_acc[mt][nt][r] : -1e30f;
        s_acc[mt][nt][r] = sv;
        rm[mt][r] = fmaxf(rm[mt][r], sv);
      }
    }
  // reduce max over the 16-lane col group, then cross-wave via LDS
#pragma unroll
  for (int off = 1; off < 16; off <<= 1)
#pragma unroll
    for (int mt = 0; mt < 4; mt++)
#pragma unroll
      for (int r = 0; r < 4; r++)
        rm[mt][r] = fmaxf(rm[mt][r], __shfl_xor(rm[mt][r], off));
  if (fm == 0)
#pragma unroll
    for (int mt = 0; mt < 4; mt++)
#pragma unroll
      for (int r = 0; r < 4; r++)
        redm[w * 64 + mt * 16 + quad * 4 + r] = rm[mt][r];
  __syncthreads();
  float fmx[4][4];
#pragma unroll
  for (int mt = 0; mt < 4; mt++)
#pragma unroll
    for (int r = 0; r < 4; r++) {
      int row = mt * 16 + quad * 4 + r;
      fmx[mt][r] = fmaxf(fmaxf(redm[row], redm[64 + row]),
                         fmaxf(redm[128 + row], redm[192 + row]));
    }
  // exp + row sum (masked entries underflow to exactly 0)
  float rs[4][4];
#pragma unroll
  for (int mt = 0; mt < 4; mt++)
#pragma unroll
    for (int r = 0; r < 4; r++) rs[mt][r] = 0.f;
#pragma unroll
  for (int mt = 0; mt < 4; mt++)
#pragma unroll
    for (int nt = 0; nt < 3; nt++)
#pragma unroll
      for (int r = 0; r < 4; r++) {
        float e = __expf(s_acc[mt][nt][r] - fmx[mt][r]);
        s_acc[mt][nt][r] = e;
        rs[mt][r] += e;
      }
#pragma unroll
  for (int off = 1; off < 16; off <<= 1)
#pragma unroll
    for (int mt = 0; mt < 4; mt++)
#pragma unroll
      for (int r = 0; r < 4; r++) rs[mt][r] += __shfl_xor(rs[mt][r], off);
  if (fm == 0)
#pragma unroll
    for (int mt = 0; mt < 4; mt++)
#pragma unroll
      for (int r = 0; r < 4; r++)
        reds[w * 64 + mt * 16 + quad * 4 + r] = rs[mt][r];
  __syncthreads();  // also guarantees all K_lds reads done before P overwrites
  float inv[4][4];
#pragma unroll
  for (int mt = 0; mt < 4; mt++)
#pragma unroll
    for (int r = 0; r < 4; r++) {
      int row = mt * 16 + quad * 4 + r;
      inv[mt][r] =
          1.0f / (reds[row] + reds[64 + row] + reds[128 + row] + reds[192 + row]);
    }
  // write P (bf16) into KP_s region with stride VSTR (C layout -> memory)
#pragma unroll
  for (int mt = 0; mt < 4; mt++)
#pragma unroll
    for (int nt = 0; nt < 3; nt++) {
      int col = n0s + nt * 16 + fm;
#pragma unroll
      for (int r = 0; r < 4; r++) {
        int row = mt * 16 + quad * 4 + r;
        KP_s[row * VSTR + col] = f2bf(s_acc[mt][nt][r] * inv[mt][r]);
      }
    }
  __syncthreads();

  // ctx = P @ V ; wave covers dh-cols [w*16, w*16+16)
  const int n0v = w * 16;
  f32x4 o_acc[4];
#pragma unroll
  for (int mt = 0; mt < 4; mt++) o_acc[mt] = (f32x4){0.f, 0.f, 0.f, 0.f};
#pragma unroll
  for (int ks = 0; ks < 6; ks++) {
    bf16x8 bv = *(const bf16x8*)&Vt_s[(n0v + fm) * VSTR + ks * 32 + quad * 8];
#pragma unroll
    for (int mt = 0; mt < 4; mt++) {
      bf16x8 ap = *(const bf16x8*)&KP_s[(mt * 16 + fm) * VSTR + ks * 32 + quad * 8];
      o_acc[mt] = MFMA(ap, bv, o_acc[mt]);
    }
  }
  // write ctx split hi/lo [B*T, 512]
  const int bb = bh >> 3, h = bh & 7;
#pragma unroll
  for (int mt = 0; mt < 4; mt++)
#pragma unroll
    for (int r = 0; r < 4; r++) {
      int t = q0 + mt * 16 + quad * 4 + r;
      int c = h * 64 + n0v + fm;
      float v = o_acc[mt][r];
      unsigned short hv = f2bf(v);
      size_t o = ((size_t)(bb * 2048 + t)) * 512 + c;
      ctx_hi[o] = hv;
      ctx_lo[o] = f2bf(v - bf2f(hv));
    }
}

// ---------------------------------------------------------------------------
// K4: out[b,e,t] = relu(attn[b,t,e] * x[b,e,t]); LDS tile transpose
__global__ __launch_bounds__(256) void k_final(const float* __restrict__ attn,
                                               const float* __restrict__ x,
                                               float* __restrict__ out) {
  __shared__ float tile[32][33];
  const int b = blockIdx.z, e0 = blockIdx.y * 32, t0 = blockIdx.x * 32;
  const int j = threadIdx.x & 31, i = threadIdx.x >> 5;
#pragma unroll
  for (int rr = 0; rr < 4; rr++) {
    int t = t0 + i + rr * 8;
    tile[i + rr * 8][j] = attn[((size_t)b * 2048 + t) * 512 + e0 + j];
  }
  __syncthreads();
#pragma unroll
  for (int rr = 0; rr < 4; rr++) {
    int e = e0 + i + rr * 8;
    size_t o = ((size_t)b * 512 + e) * 2048 + t0 + j;
    float v = tile[j][i + rr * 8] * x[o];
    out[o] = fmaxf(v, 0.f);
  }
}

// ---------------------------------------------------------------------------
extern "C" void kernel_launch(void* const* d_in, const int* in_sizes, int n_in,
                              void* d_out, int out_size, void* d_ws, size_t ws_size,
                              hipStream_t stream) {
  const float* x = (const float*)d_in[0];
  const float* w_in = (const float*)d_in[1];
  const float* b_in = (const float*)d_in[2];
  const float* w_out = (const float*)d_in[3];
  const float* b_out = (const float*)d_in[4];
  float* out = (float*)d_out;

  uint8_t* ws = (uint8_t*)d_ws;
  unsigned short* xT_hi = (unsigned short*)(ws + 0);           // 4 MiB
  unsigned short* xT_lo = (unsigned short*)(ws + 4194304);     // 4 MiB
  unsigned short* wih   = (unsigned short*)(ws + 8388608);     // 1.5 MiB
  unsigned short* wil   = (unsigned short*)(ws + 9961472);     // 1.5 MiB
  unsigned short* woh   = (unsigned short*)(ws + 11534336);    // 0.5 MiB
  unsigned short* wol   = (unsigned short*)(ws + 12058624);    // 0.5 MiB
  unsigned short* Qs    = (unsigned short*)(ws + 12582912);    // 4 MiB
  unsigned short* Kk    = (unsigned short*)(ws + 16777216);    // 4 MiB
  unsigned short* Vv    = (unsigned short*)(ws + 20971520);    // 4 MiB
  unsigned short* ctxh  = (unsigned short*)(ws + 25165824);    // 4 MiB
  unsigned short* ctxl  = (unsigned short*)(ws + 29360128);    // 4 MiB
  float* attnf          = (float*)(ws + 33554432);             // 8 MiB

  k_transpose_split_x<<<dim3(64, 16, 2), 256, 0, stream>>>(x, xT_hi, xT_lo);
  k_split_convert<<<3072, 256, 0, stream>>>(w_in, wih, wil, 786432);
  k_split_convert<<<1024, 256, 0, stream>>>(w_out, woh, wol, 262144);
  k_gemm_split<<<dim3(12, 32), 256, 0, stream>>>(xT_hi, xT_lo, wih, wil, b_in, 0,
                                                 Qs, Kk, Vv, nullptr);
  k_attention<<<dim3(32, 16), 256, 0, stream>>>(Qs, Kk, Vv, ctxh, ctxl);
  k_gemm_split<<<dim3(4, 32), 256, 0, stream>>>(ctxh, ctxl, woh, wol, b_out, 1,
                                                nullptr, nullptr, nullptr, attnf);
  k_final<<<dim3(64, 16, 2), 256, 0, stream>>>(attnf, x, out);
}

// Round 2
// 131.633 us; speedup vs baseline: 1.2237x; 1.2237x over previous
//
#include <hip/hip_runtime.h>
#include <stdint.h>

// Encoder: B=2,E=512,T=2048,H=8,dh=64, local window |i-j|<=64
// R2: 2-pass split GEMM (A=hi+lo, W=hi only; err budget 2-3x margin),
//     out-proj 64x128 tile (256 blocks), vectorized V staging in attention,
//     merged weight-convert dispatch.

#define DEVI __device__ __forceinline__

typedef __attribute__((ext_vector_type(8))) short bf16x8;   // 8 bf16 in 4 VGPRs
typedef __attribute__((ext_vector_type(4))) float f32x4;

DEVI unsigned short f2bf(float f) {               // RNE float->bf16
  unsigned u = __float_as_uint(f);
  u += 0x7fffu + ((u >> 16) & 1u);
  return (unsigned short)(u >> 16);
}
DEVI float bf2f(unsigned short h) { return __uint_as_float(((unsigned)h) << 16); }

#define GLL16(gp, lp)                                                          \
  __builtin_amdgcn_global_load_lds(                                            \
      (const __attribute__((address_space(1))) void*)(gp),                     \
      (__attribute__((address_space(3))) void*)(lp), 16, 0, 0)

#define MFMA(a, b, c) __builtin_amdgcn_mfma_f32_16x16x32_bf16((a), (b), (c), 0, 0, 0)

// ---------------------------------------------------------------------------
// K0a: x[B,E,T] fp32 -> xT[B*T, 512] split bf16 (hi/lo), LDS tile transpose
__global__ __launch_bounds__(256) void k_transpose_split_x(
    const float* __restrict__ x, unsigned short* __restrict__ xh,
    unsigned short* __restrict__ xl) {
  __shared__ float tile[32][33];
  const int b = blockIdx.z, e0 = blockIdx.y * 32, t0 = blockIdx.x * 32;
  const int j = threadIdx.x & 31, i = threadIdx.x >> 5;  // i: 0..7
#pragma unroll
  for (int rr = 0; rr < 4; rr++) {
    int e = e0 + i + rr * 8;
    tile[i + rr * 8][j] = x[((size_t)b * 512 + e) * 2048 + t0 + j];  // coalesced t
  }
  __syncthreads();
#pragma unroll
  for (int rr = 0; rr < 4; rr++) {
    int t = t0 + i + rr * 8;
    float v = tile[j][i + rr * 8];
    size_t o = ((size_t)b * 2048 + t) * 512 + e0 + j;  // coalesced e
    unsigned short hv = f2bf(v);
    xh[o] = hv;
    xl[o] = f2bf(v - bf2f(hv));
  }
}

// K0b: both weight tensors -> bf16 hi, single dispatch
__global__ __launch_bounds__(256) void k_convert_w(
    const float* __restrict__ w_in, const float* __restrict__ w_out,
    unsigned short* __restrict__ wih, unsigned short* __restrict__ woh) {
  int i = blockIdx.x * 256 + threadIdx.x;
  if (i < 786432) {
    wih[i] = f2bf(w_in[i]);
  } else if (i < 786432 + 262144) {
    int j = i - 786432;
    woh[j] = f2bf(w_out[j]);
  }
}

// ---------------------------------------------------------------------------
// 2-pass split GEMM: C[m,n] = sum_k (Ah+Al)[m,k]*Bh[n,k] + bias[n]
// Tile MT x 128, BK=32, 4 waves (wave tile MT/2 x 64).
// MT=128: scatter into Q(*0.125)/K/V [B,H,T,64] bf16.  MT=64: fp32 [M,512].
template <int MT>
__global__ __launch_bounds__(256) void k_gemm_split(
    const unsigned short* __restrict__ Ahg, const unsigned short* __restrict__ Alg,
    const unsigned short* __restrict__ Bhg, const float* __restrict__ bias,
    unsigned short* __restrict__ Qs, unsigned short* __restrict__ Kks,
    unsigned short* __restrict__ Vvs, float* __restrict__ attn_out) {
  const int KD = 512;
  constexpr int AI = MT / 32;      // m-subtiles per wave
  constexpr int AC = MT / 64;      // A GLL16 calls per wave per array
  __shared__ __align__(16) unsigned short Ah_s[MT * 32];
  __shared__ __align__(16) unsigned short Al_s[MT * 32];
  __shared__ __align__(16) unsigned short Bh_s[128 * 32];
  const int tid = threadIdx.x, lane = tid & 63, w = tid >> 6;
  const int m0 = blockIdx.y * MT, n0 = blockIdx.x * 128;
  const int wm = (w >> 1) * (MT / 2), wn = (w & 1) * 64;

  f32x4 acc[AI][4];
#pragma unroll
  for (int i = 0; i < AI; i++)
#pragma unroll
    for (int j = 0; j < 4; j++) acc[i][j] = (f32x4){0.f, 0.f, 0.f, 0.f};

  // staging: one GLL16 call = 16 rows x 32 cols (1KB), lane off = lane*16B
  const int srw = lane >> 2, sc = (lane & 3) * 8;
  const size_t b0 = (size_t)(n0 + w * 32 + srw) * KD + sc;
  const size_t b1 = b0 + (size_t)16 * KD;
  unsigned short* lB0 = &Bh_s[(w * 32) * 32];
  unsigned short* lB1 = &Bh_s[(w * 32 + 16) * 32];
  size_t aoff[AC];
  unsigned short* lAh[AC];
  unsigned short* lAl[AC];
#pragma unroll
  for (int c = 0; c < AC; c++) {
    int rbase = w * (MT / 4) + c * 16;
    aoff[c] = (size_t)(m0 + rbase + srw) * KD + sc;
    lAh[c] = &Ah_s[rbase * 32];
    lAl[c] = &Al_s[rbase * 32];
  }

  const int fm = lane & 15, fq = (lane >> 4) * 8;

  for (int k0 = 0; k0 < KD; k0 += 32) {
    __syncthreads();
#pragma unroll
    for (int c = 0; c < AC; c++) {
      GLL16(Ahg + aoff[c] + k0, lAh[c]);
      GLL16(Alg + aoff[c] + k0, lAl[c]);
    }
    GLL16(Bhg + b0 + k0, lB0);
    GLL16(Bhg + b1 + k0, lB1);
    __builtin_amdgcn_s_waitcnt(0);
    __syncthreads();

    bf16x8 ah[AI], al[AI], bh[4];
#pragma unroll
    for (int i = 0; i < AI; i++) {
      ah[i] = *(const bf16x8*)&Ah_s[(wm + i * 16 + fm) * 32 + fq];
      al[i] = *(const bf16x8*)&Al_s[(wm + i * 16 + fm) * 32 + fq];
    }
#pragma unroll
    for (int j = 0; j < 4; j++)
      bh[j] = *(const bf16x8*)&Bh_s[(wn + j * 16 + fm) * 32 + fq];
#pragma unroll
    for (int i = 0; i < AI; i++)
#pragma unroll
      for (int j = 0; j < 4; j++) {
        acc[i][j] = MFMA(ah[i], bh[j], acc[i][j]);
        acc[i][j] = MFMA(al[i], bh[j], acc[i][j]);
      }
  }

  // epilogue: C/D layout col=lane&15, row=quad*4+r  [m89-verified]
  const int quad = lane >> 4;
#pragma unroll
  for (int i = 0; i < AI; i++)
#pragma unroll
    for (int j = 0; j < 4; j++) {
      int gn = n0 + wn + j * 16 + fm;
      float bv = bias[gn];
#pragma unroll
      for (int r = 0; r < 4; r++) {
        int gm = m0 + wm + i * 16 + quad * 4 + r;
        float v = acc[i][j][r] + bv;
        if (MT == 128) {
          int bb = gm >> 11, t = gm & 2047;
          int sec = gn >> 9, cc = gn & 511;
          int h = cc >> 6, d = cc & 63;
          if (sec == 0) v *= 0.125f;  // 1/sqrt(64), exact
          unsigned short* dst = sec == 0 ? Qs : (sec == 1 ? Kks : Vvs);
          dst[(((size_t)(bb * 8 + h)) * 2048 + t) * 64 + d] = f2bf(v);
        } else {
          attn_out[(size_t)gm * 512 + gn] = v;
        }
      }
    }
}

// ---------------------------------------------------------------------------
// K2: local attention. Block = (b,h, 64 queries). Window = 192 keys.
#define KSTR 88   // K_lds row stride (bf16): 176B, 2-way-free b128 reads
#define VSTR 216  // Vt/P row stride (bf16): 432B, 2-way-free b128 reads
__global__ __launch_bounds__(256) void k_attention(
    const unsigned short* __restrict__ Qs, const unsigned short* __restrict__ Kks,
    const unsigned short* __restrict__ Vvs, unsigned short* __restrict__ ctx_hi,
    unsigned short* __restrict__ ctx_lo) {
  __shared__ __align__(16) unsigned short KP_s[192 * KSTR];  // K, later P (64 x VSTR)
  __shared__ __align__(16) unsigned short Vt_s[64 * VSTR];   // V^T [dh][key]
  __shared__ float redm[4 * 64];
  __shared__ float reds[4 * 64];

  const int tid = threadIdx.x, lane = tid & 63, w = tid >> 6;
  const int q0 = blockIdx.x * 64;
  const int bh = blockIdx.y;
  const int j0 = q0 - 64;
  const size_t base = (size_t)bh * 2048 * 64;

  // stage K rows (clamped; garbage rows are masked before softmax)
  for (int idx = tid; idx < 192 * 8; idx += 256) {
    int r = idx >> 3, c = idx & 7;
    int j = j0 + r;
    j = j < 0 ? 0 : (j > 2047 ? 2047 : j);
    uint4 v = *(const uint4*)&Kks[base + (size_t)j * 64 + c * 8];
    *(uint4*)&KP_s[r * KSTR + c * 8] = v;
  }
  // stage V transposed: vector global load (8 shorts) + LDS transpose scatter
  for (int idx = tid; idx < 192 * 8; idx += 256) {
    int r = idx >> 3, c8 = (idx & 7) * 8;
    int j = j0 + r;
    uint4 v;
    if (j >= 0 && j < 2048)
      v = *(const uint4*)&Vvs[base + (size_t)j * 64 + c8];
    else
      v = (uint4){0u, 0u, 0u, 0u};  // OOB rows ZERO (0*garbage hazard)
    const unsigned short* e = (const unsigned short*)&v;
#pragma unroll
    for (int u = 0; u < 8; u++) Vt_s[(c8 + u) * VSTR + r] = e[u];
  }

  // Q fragments straight from global (A layout: m=lane&15, k=quad*8+j)
  const int fm = lane & 15, quad = lane >> 4;
  bf16x8 aq[4][2];
#pragma unroll
  for (int mt = 0; mt < 4; mt++)
#pragma unroll
    for (int ks = 0; ks < 2; ks++)
      aq[mt][ks] = *(const bf16x8*)&Qs[base + (size_t)(q0 + mt * 16 + fm) * 64 +
                                       ks * 32 + quad * 8];
  __syncthreads();

  // S = Qs @ K^T ; wave covers key-cols [w*48, w*48+48)
  const int n0s = w * 48;
  f32x4 s_acc[4][3];
#pragma unroll
  for (int mt = 0; mt < 4; mt++)
#pragma unroll
    for (int nt = 0; nt < 3; nt++) s_acc[mt][nt] = (f32x4){0.f, 0.f, 0.f, 0.f};
#pragma unroll
  for (int nt = 0; nt < 3; nt++)
#pragma unroll
    for (int ks = 0; ks < 2; ks++) {
      bf16x8 bk =
          *(const bf16x8*)&KP_s[(n0s + nt * 16 + fm) * KSTR + ks * 32 + quad * 8];
#pragma unroll
      for (int mt = 0; mt < 4; mt++) s_acc[mt][nt] = MFMA(aq[mt][ks], bk, s_acc[mt][nt]);
    }

  // mask (REPLACE, not add) + per-row max
  float rm[4][4];
#pragma unroll
  for (int mt = 0; mt < 4; mt++)
#pragma unroll
    for (int r = 0; r < 4; r++) rm[mt][r] = -1e30f;
#pragma unroll
  for (int mt = 0; mt < 4; mt++)
#pragma unroll
    for (int nt = 0; nt < 3; nt++) {
      int jj = n0s + nt * 16 + fm;
      int jg = j0 + jj;
#pragma unroll
      for (int r = 0; r < 4; r++) {
        int ii = mt * 16 + quad * 4 + r;
        bool ok = (jj >= ii) && (jj <= ii + 128) && (jg >= 0) && (jg < 2048);
        float sv = ok ? s_acc[mt][nt][r] : -1e30f;
        s_acc[mt][nt][r] = sv;
        rm[mt][r] = fmaxf(rm[mt][r], sv);
      }
    }
  // reduce max over the 16-lane col group, then cross-wave via LDS
#pragma unroll
  for (int off = 1; off < 16; off <<= 1)
#pragma unroll
    for (int mt = 0; mt < 4; mt++)
#pragma unroll
      for (int r = 0; r < 4; r++)
        rm[mt][r] = fmaxf(rm[mt][r], __shfl_xor(rm[mt][r], off));
  if (fm == 0)
#pragma unroll
    for (int mt = 0; mt < 4; mt++)
#pragma unroll
      for (int r = 0; r < 4; r++)
        redm[w * 64 + mt * 16 + quad * 4 + r] = rm[mt][r];
  __syncthreads();
  float fmx[4][4];
#pragma unroll
  for (int mt = 0; mt < 4; mt++)
#pragma unroll
    for (int r = 0; r < 4; r++) {
      int row = mt * 16 + quad * 4 + r;
      fmx[mt][r] = fmaxf(fmaxf(redm[row], redm[64 + row]),
                         fmaxf(redm[128 + row], redm[192 + row]));
    }
  // exp + row sum (masked entries underflow to exactly 0)
  float rs[4][4];
#pragma unroll
  for (int mt = 0; mt < 4; mt++)
#pragma unroll
    for (int r = 0; r < 4; r++) rs[mt][r] = 0.f;
#pragma unroll
  for (int mt = 0; mt < 4; mt++)
#pragma unroll
    for (int nt = 0; nt < 3; nt++)
#pragma unroll
      for (int r = 0; r < 4; r++) {
        float e = __expf(s_acc[mt][nt][r] - fmx[mt][r]);
        s_acc[mt][nt][r] = e;
        rs[mt][r] += e;
      }
#pragma unroll
  for (int off = 1; off < 16; off <<= 1)
#pragma unroll
    for (int mt = 0; mt < 4; mt++)
#pragma unroll
      for (int r = 0; r < 4; r++) rs[mt][r] += __shfl_xor(rs[mt][r], off);
  if (fm == 0)
#pragma unroll
    for (int mt = 0; mt < 4; mt++)
#pragma unroll
      for (int r = 0; r < 4; r++)
        reds[w * 64 + mt * 16 + quad * 4 + r] = rs[mt][r];
  __syncthreads();  // also guarantees all K_lds reads done before P overwrites
  float inv[4][4];
#pragma unroll
  for (int mt = 0; mt < 4; mt++)
#pragma unroll
    for (int r = 0; r < 4; r++) {
      int row = mt * 16 + quad * 4 + r;
      inv[mt][r] =
          1.0f / (reds[row] + reds[64 + row] + reds[128 + row] + reds[192 + row]);
    }
  // write P (bf16) into KP_s region with stride VSTR (C layout -> memory)
#pragma unroll
  for (int mt = 0; mt < 4; mt++)
#pragma unroll
    for (int nt = 0; nt < 3; nt++) {
      int col = n0s + nt * 16 + fm;
#pragma unroll
      for (int r = 0; r < 4; r++) {
        int row = mt * 16 + quad * 4 + r;
        KP_s[row * VSTR + col] = f2bf(s_acc[mt][nt][r] * inv[mt][r]);
      }
    }
  __syncthreads();

  // ctx = P @ V ; wave covers dh-cols [w*16, w*16+16)
  const int n0v = w * 16;
  f32x4 o_acc[4];
#pragma unroll
  for (int mt = 0; mt < 4; mt++) o_acc[mt] = (f32x4){0.f, 0.f, 0.f, 0.f};
#pragma unroll
  for (int ks = 0; ks < 6; ks++) {
    bf16x8 bv = *(const bf16x8*)&Vt_s[(n0v + fm) * VSTR + ks * 32 + quad * 8];
#pragma unroll
    for (int mt = 0; mt < 4; mt++) {
      bf16x8 ap = *(const bf16x8*)&KP_s[(mt * 16 + fm) * VSTR + ks * 32 + quad * 8];
      o_acc[mt] = MFMA(ap, bv, o_acc[mt]);
    }
  }
  // write ctx split hi/lo [B*T, 512]
  const int bb = bh >> 3, h = bh & 7;
#pragma unroll
  for (int mt = 0; mt < 4; mt++)
#pragma unroll
    for (int r = 0; r < 4; r++) {
      int t = q0 + mt * 16 + quad * 4 + r;
      int c = h * 64 + n0v + fm;
      float v = o_acc[mt][r];
      unsigned short hv = f2bf(v);
      size_t o = ((size_t)(bb * 2048 + t)) * 512 + c;
      ctx_hi[o] = hv;
      ctx_lo[o] = f2bf(v - bf2f(hv));
    }
}

// ---------------------------------------------------------------------------
// K4: out[b,e,t] = relu(attn[b,t,e] * x[b,e,t]); LDS tile transpose
__global__ __launch_bounds__(256) void k_final(const float* __restrict__ attn,
                                               const float* __restrict__ x,
                                               float* __restrict__ out) {
  __shared__ float tile[32][33];
  const int b = blockIdx.z, e0 = blockIdx.y * 32, t0 = blockIdx.x * 32;
  const int j = threadIdx.x & 31, i = threadIdx.x >> 5;
#pragma unroll
  for (int rr = 0; rr < 4; rr++) {
    int t = t0 + i + rr * 8;
    tile[i + rr * 8][j] = attn[((size_t)b * 2048 + t) * 512 + e0 + j];
  }
  __syncthreads();
#pragma unroll
  for (int rr = 0; rr < 4; rr++) {
    int e = e0 + i + rr * 8;
    size_t o = ((size_t)b * 512 + e) * 2048 + t0 + j;
    float v = tile[j][i + rr * 8] * x[o];
    out[o] = fmaxf(v, 0.f);
  }
}

// ---------------------------------------------------------------------------
extern "C" void kernel_launch(void* const* d_in, const int* in_sizes, int n_in,
                              void* d_out, int out_size, void* d_ws, size_t ws_size,
                              hipStream_t stream) {
  const float* x = (const float*)d_in[0];
  const float* w_in = (const float*)d_in[1];
  const float* b_in = (const float*)d_in[2];
  const float* w_out = (const float*)d_in[3];
  const float* b_out = (const float*)d_in[4];
  float* out = (float*)d_out;

  uint8_t* ws = (uint8_t*)d_ws;
  unsigned short* xT_hi = (unsigned short*)(ws + 0);           // 4 MiB
  unsigned short* xT_lo = (unsigned short*)(ws + 4194304);     // 4 MiB
  unsigned short* wih   = (unsigned short*)(ws + 8388608);     // 1.5 MiB
  unsigned short* woh   = (unsigned short*)(ws + 9961472);     // 0.5 MiB
  unsigned short* Qs    = (unsigned short*)(ws + 12582912);    // 4 MiB
  unsigned short* Kk    = (unsigned short*)(ws + 16777216);    // 4 MiB
  unsigned short* Vv    = (unsigned short*)(ws + 20971520);    // 4 MiB
  unsigned short* ctxh  = (unsigned short*)(ws + 25165824);    // 4 MiB
  unsigned short* ctxl  = (unsigned short*)(ws + 29360128);    // 4 MiB
  float* attnf          = (float*)(ws + 33554432);             // 8 MiB

  k_transpose_split_x<<<dim3(64, 16, 2), 256, 0, stream>>>(x, xT_hi, xT_lo);
  k_convert_w<<<4096, 256, 0, stream>>>(w_in, w_out, wih, woh);
  k_gemm_split<128><<<dim3(12, 32), 256, 0, stream>>>(xT_hi, xT_lo, wih, b_in,
                                                      Qs, Kk, Vv, nullptr);
  k_attention<<<dim3(32, 16), 256, 0, stream>>>(Qs, Kk, Vv, ctxh, ctxl);
  k_gemm_split<64><<<dim3(4, 64), 256, 0, stream>>>(ctxh, ctxl, woh, b_out,
                                                    nullptr, nullptr, nullptr,
                                                    attnf);
  k_final<<<dim3(64, 16, 2), 256, 0, stream>>>(attnf, x, out);
}

// Round 3
// 126.146 us; speedup vs baseline: 1.2769x; 1.0435x over previous
//
#include <hip/hip_runtime.h>
#include <stdint.h>

// Encoder: B=2,E=512,T=2048,H=8,dh=64, local window |i-j|<=64
// R3: fuse out-proj GEMM epilogue with transpose*x+relu (kills attnf roundtrip
//     + 1 dispatch); fold weight-convert into transpose kernel grid.
//     QKV GEMM + attention unchanged (LDS-BW-bound analysis says leave inner
//     loop alone this round).

#define DEVI __device__ __forceinline__

typedef __attribute__((ext_vector_type(8))) short bf16x8;   // 8 bf16 in 4 VGPRs
typedef __attribute__((ext_vector_type(4))) float f32x4;

DEVI unsigned short f2bf(float f) {               // RNE float->bf16
  unsigned u = __float_as_uint(f);
  u += 0x7fffu + ((u >> 16) & 1u);
  return (unsigned short)(u >> 16);
}
DEVI float bf2f(unsigned short h) { return __uint_as_float(((unsigned)h) << 16); }

#define GLL16(gp, lp)                                                          \
  __builtin_amdgcn_global_load_lds(                                            \
      (const __attribute__((address_space(1))) void*)(gp),                     \
      (__attribute__((address_space(3))) void*)(lp), 16, 0, 0)

#define MFMA(a, b, c) __builtin_amdgcn_mfma_f32_16x16x32_bf16((a), (b), (c), 0, 0, 0)

// ---------------------------------------------------------------------------
// K0: blockIdx.y<16: x[B,E,T] fp32 -> xT[B*T,512] split bf16 hi/lo (transpose)
//     blockIdx.y==16: w_in/w_out fp32 -> bf16 hi (128 rider blocks)
__global__ __launch_bounds__(256) void k_prep(
    const float* __restrict__ x, const float* __restrict__ w_in,
    const float* __restrict__ w_out, unsigned short* __restrict__ xh,
    unsigned short* __restrict__ xl, unsigned short* __restrict__ wih,
    unsigned short* __restrict__ woh) {
  const int tid = threadIdx.x;
  if (blockIdx.y == 16) {  // weight convert rider: 128 blocks x 8192 elems
    int cb = (blockIdx.z << 6) | blockIdx.x;
    const float* src;
    unsigned short* dst;
    int base;
    if (cb < 96) {        // 96*8192 = 786432 = w_in exactly
      src = w_in; dst = wih; base = cb * 8192;
    } else {              // 32*8192 = 262144 = w_out exactly
      src = w_out; dst = woh; base = (cb - 96) * 8192;
    }
#pragma unroll
    for (int k = 0; k < 8; k++) {
      int idx = base + (k * 256 + tid) * 4;
      float4 v = *(const float4*)&src[idx];
      ushort4 o;
      o.x = f2bf(v.x); o.y = f2bf(v.y); o.z = f2bf(v.z); o.w = f2bf(v.w);
      *(ushort4*)&dst[idx] = o;
    }
    return;
  }
  __shared__ float tile[32][33];
  const int b = blockIdx.z, e0 = blockIdx.y * 32, t0 = blockIdx.x * 32;
  const int j = tid & 31, i = tid >> 5;  // i: 0..7
#pragma unroll
  for (int rr = 0; rr < 4; rr++) {
    int e = e0 + i + rr * 8;
    tile[i + rr * 8][j] = x[((size_t)b * 512 + e) * 2048 + t0 + j];  // coalesced t
  }
  __syncthreads();
#pragma unroll
  for (int rr = 0; rr < 4; rr++) {
    int t = t0 + i + rr * 8;
    float v = tile[j][i + rr * 8];
    size_t o = ((size_t)b * 2048 + t) * 512 + e0 + j;  // coalesced e
    unsigned short hv = f2bf(v);
    xh[o] = hv;
    xl[o] = f2bf(v - bf2f(hv));
  }
}

// ---------------------------------------------------------------------------
// QKV GEMM: C[m,n] = sum_k (Ah+Al)[m,k]*Bh[n,k] + bias[n], 128x128 tile, BK=32.
// Epilogue scatters into Q(*0.125)/K/V [B,H,T,64] bf16.
__global__ __launch_bounds__(256) void k_gemm_qkv(
    const unsigned short* __restrict__ Ahg, const unsigned short* __restrict__ Alg,
    const unsigned short* __restrict__ Bhg, const float* __restrict__ bias,
    unsigned short* __restrict__ Qs, unsigned short* __restrict__ Kks,
    unsigned short* __restrict__ Vvs) {
  const int KD = 512;
  __shared__ __align__(16) unsigned short Ah_s[128 * 32];
  __shared__ __align__(16) unsigned short Al_s[128 * 32];
  __shared__ __align__(16) unsigned short Bh_s[128 * 32];
  const int tid = threadIdx.x, lane = tid & 63, w = tid >> 6;
  const int m0 = blockIdx.y * 128, n0 = blockIdx.x * 128;
  const int wm = (w >> 1) * 64, wn = (w & 1) * 64;

  f32x4 acc[4][4];
#pragma unroll
  for (int i = 0; i < 4; i++)
#pragma unroll
    for (int j = 0; j < 4; j++) acc[i][j] = (f32x4){0.f, 0.f, 0.f, 0.f};

  const int srw = lane >> 2, sc = (lane & 3) * 8;
  const size_t b0 = (size_t)(n0 + w * 32 + srw) * KD + sc;
  const size_t b1 = b0 + (size_t)16 * KD;
  unsigned short* lB0 = &Bh_s[(w * 32) * 32];
  unsigned short* lB1 = &Bh_s[(w * 32 + 16) * 32];
  const size_t a0 = (size_t)(m0 + w * 32 + srw) * KD + sc;
  const size_t a1 = a0 + (size_t)16 * KD;
  unsigned short* lAh0 = &Ah_s[(w * 32) * 32];
  unsigned short* lAh1 = &Ah_s[(w * 32 + 16) * 32];
  unsigned short* lAl0 = &Al_s[(w * 32) * 32];
  unsigned short* lAl1 = &Al_s[(w * 32 + 16) * 32];

  const int fm = lane & 15, fq = (lane >> 4) * 8;

  for (int k0 = 0; k0 < KD; k0 += 32) {
    __syncthreads();
    GLL16(Ahg + a0 + k0, lAh0);
    GLL16(Ahg + a1 + k0, lAh1);
    GLL16(Alg + a0 + k0, lAl0);
    GLL16(Alg + a1 + k0, lAl1);
    GLL16(Bhg + b0 + k0, lB0);
    GLL16(Bhg + b1 + k0, lB1);
    __builtin_amdgcn_s_waitcnt(0);
    __syncthreads();

    bf16x8 ah[4], al[4], bh[4];
#pragma unroll
    for (int i = 0; i < 4; i++) {
      ah[i] = *(const bf16x8*)&Ah_s[(wm + i * 16 + fm) * 32 + fq];
      al[i] = *(const bf16x8*)&Al_s[(wm + i * 16 + fm) * 32 + fq];
      bh[i] = *(const bf16x8*)&Bh_s[(wn + i * 16 + fm) * 32 + fq];
    }
#pragma unroll
    for (int i = 0; i < 4; i++)
#pragma unroll
      for (int j = 0; j < 4; j++) {
        acc[i][j] = MFMA(ah[i], bh[j], acc[i][j]);
        acc[i][j] = MFMA(al[i], bh[j], acc[i][j]);
      }
  }

  // epilogue: C/D layout col=lane&15, row=quad*4+r  [m89-verified]
  const int quad = lane >> 4;
#pragma unroll
  for (int i = 0; i < 4; i++)
#pragma unroll
    for (int j = 0; j < 4; j++) {
      int gn = n0 + wn + j * 16 + fm;
      float bv = bias[gn];
      int sec = gn >> 9, cc = gn & 511;
      int h = cc >> 6, d = cc & 63;
      unsigned short* dst = sec == 0 ? Qs : (sec == 1 ? Kks : Vvs);
      float mul = sec == 0 ? 0.125f : 1.0f;  // 1/sqrt(64), exact
#pragma unroll
      for (int r = 0; r < 4; r++) {
        int gm = m0 + wm + i * 16 + quad * 4 + r;
        int bb = gm >> 11, t = gm & 2047;
        float v = (acc[i][j][r] + bv) * mul;
        dst[(((size_t)(bb * 8 + h)) * 2048 + t) * 64 + d] = f2bf(v);
      }
    }
}

// ---------------------------------------------------------------------------
// Out-proj GEMM fused with final transpose * x + relu.
// C[m,n] = sum_k (Ah+Al)[m,k]*Bh[n,k] + bias[n]; tile 64m x 128n, grid 256.
// Epilogue: LDS transpose -> out[b,e,t] = relu(C[b,t,e] * x[b,e,t]).
__global__ __launch_bounds__(256) void k_gemm_out(
    const unsigned short* __restrict__ Ahg, const unsigned short* __restrict__ Alg,
    const unsigned short* __restrict__ Bhg, const float* __restrict__ bias,
    const float* __restrict__ x, float* __restrict__ out) {
  const int KD = 512;
  __shared__ __align__(16) union {
    struct {
      unsigned short Ah[64 * 32];
      unsigned short Al[64 * 32];
      unsigned short Bh[128 * 32];
    } st;                       // 16 KB staging
    float tile[64][129];        // 32.25 KB epilogue transpose
  } u;
  const int tid = threadIdx.x, lane = tid & 63, w = tid >> 6;
  const int m0 = blockIdx.y * 64, n0 = blockIdx.x * 128;
  const int wm = (w >> 1) * 32, wn = (w & 1) * 64;

  f32x4 acc[2][4];
#pragma unroll
  for (int i = 0; i < 2; i++)
#pragma unroll
    for (int j = 0; j < 4; j++) acc[i][j] = (f32x4){0.f, 0.f, 0.f, 0.f};

  const int srw = lane >> 2, sc = (lane & 3) * 8;
  const size_t b0 = (size_t)(n0 + w * 32 + srw) * KD + sc;
  const size_t b1 = b0 + (size_t)16 * KD;
  const size_t a0 = (size_t)(m0 + w * 16 + srw) * KD + sc;
  unsigned short* lB0 = &u.st.Bh[(w * 32) * 32];
  unsigned short* lB1 = &u.st.Bh[(w * 32 + 16) * 32];
  unsigned short* lAh0 = &u.st.Ah[(w * 16) * 32];
  unsigned short* lAl0 = &u.st.Al[(w * 16) * 32];

  const int fm = lane & 15, fq = (lane >> 4) * 8;

  for (int k0 = 0; k0 < KD; k0 += 32) {
    __syncthreads();
    GLL16(Ahg + a0 + k0, lAh0);
    GLL16(Alg + a0 + k0, lAl0);
    GLL16(Bhg + b0 + k0, lB0);
    GLL16(Bhg + b1 + k0, lB1);
    __builtin_amdgcn_s_waitcnt(0);
    __syncthreads();

    bf16x8 ah[2], al[2], bh[4];
#pragma unroll
    for (int i = 0; i < 2; i++) {
      ah[i] = *(const bf16x8*)&u.st.Ah[(wm + i * 16 + fm) * 32 + fq];
      al[i] = *(const bf16x8*)&u.st.Al[(wm + i * 16 + fm) * 32 + fq];
    }
#pragma unroll
    for (int j = 0; j < 4; j++)
      bh[j] = *(const bf16x8*)&u.st.Bh[(wn + j * 16 + fm) * 32 + fq];
#pragma unroll
    for (int i = 0; i < 2; i++)
#pragma unroll
      for (int j = 0; j < 4; j++) {
        acc[i][j] = MFMA(ah[i], bh[j], acc[i][j]);
        acc[i][j] = MFMA(al[i], bh[j], acc[i][j]);
      }
  }

  __syncthreads();  // all frag reads done before tile overwrites staging
  // write acc+bias into transpose tile: tile[t_local][e_local]
  const int quad = lane >> 4;
#pragma unroll
  for (int i = 0; i < 2; i++)
#pragma unroll
    for (int j = 0; j < 4; j++) {
      int ln = wn + j * 16 + fm;
      float bv = bias[n0 + ln];
#pragma unroll
      for (int r = 0; r < 4; r++) {
        int lm = wm + i * 16 + quad * 4 + r;
        u.tile[lm][ln] = acc[i][j][r] + bv;
      }
    }
  __syncthreads();

  // out[b,e,t] = relu(tile[t][e] * x[b,e,t]); coalesced along t
  const int bb = m0 >> 11, t0 = m0 & 2047;
  const int tt = tid & 63, e0w = tid >> 6;
#pragma unroll
  for (int k = 0; k < 32; k++) {
    int ee = e0w + k * 4;
    size_t o = ((size_t)bb * 512 + n0 + ee) * 2048 + t0 + tt;
    float v = u.tile[tt][ee] * x[o];
    out[o] = fmaxf(v, 0.f);
  }
}

// ---------------------------------------------------------------------------
// K2: local attention. Block = (b,h, 64 queries). Window = 192 keys.
#define KSTR 88   // K_lds row stride (bf16): 176B, 2-way-free b128 reads
#define VSTR 216  // Vt/P row stride (bf16): 432B, 2-way-free b128 reads
__global__ __launch_bounds__(256) void k_attention(
    const unsigned short* __restrict__ Qs, const unsigned short* __restrict__ Kks,
    const unsigned short* __restrict__ Vvs, unsigned short* __restrict__ ctx_hi,
    unsigned short* __restrict__ ctx_lo) {
  __shared__ __align__(16) unsigned short KP_s[192 * KSTR];  // K, later P (64 x VSTR)
  __shared__ __align__(16) unsigned short Vt_s[64 * VSTR];   // V^T [dh][key]
  __shared__ float redm[4 * 64];
  __shared__ float reds[4 * 64];

  const int tid = threadIdx.x, lane = tid & 63, w = tid >> 6;
  const int q0 = blockIdx.x * 64;
  const int bh = blockIdx.y;
  const int j0 = q0 - 64;
  const size_t base = (size_t)bh * 2048 * 64;

  // stage K rows (clamped; garbage rows are masked before softmax)
  for (int idx = tid; idx < 192 * 8; idx += 256) {
    int r = idx >> 3, c = idx & 7;
    int j = j0 + r;
    j = j < 0 ? 0 : (j > 2047 ? 2047 : j);
    uint4 v = *(const uint4*)&Kks[base + (size_t)j * 64 + c * 8];
    *(uint4*)&KP_s[r * KSTR + c * 8] = v;
  }
  // stage V transposed: vector global load (8 shorts) + LDS transpose scatter
  for (int idx = tid; idx < 192 * 8; idx += 256) {
    int r = idx >> 3, c8 = (idx & 7) * 8;
    int j = j0 + r;
    uint4 v;
    if (j >= 0 && j < 2048)
      v = *(const uint4*)&Vvs[base + (size_t)j * 64 + c8];
    else
      v = (uint4){0u, 0u, 0u, 0u};  // OOB rows ZERO (0*garbage hazard)
    const unsigned short* e = (const unsigned short*)&v;
#pragma unroll
    for (int uu = 0; uu < 8; uu++) Vt_s[(c8 + uu) * VSTR + r] = e[uu];
  }

  // Q fragments straight from global (A layout: m=lane&15, k=quad*8+j)
  const int fm = lane & 15, quad = lane >> 4;
  bf16x8 aq[4][2];
#pragma unroll
  for (int mt = 0; mt < 4; mt++)
#pragma unroll
    for (int ks = 0; ks < 2; ks++)
      aq[mt][ks] = *(const bf16x8*)&Qs[base + (size_t)(q0 + mt * 16 + fm) * 64 +
                                       ks * 32 + quad * 8];
  __syncthreads();

  // S = Qs @ K^T ; wave covers key-cols [w*48, w*48+48)
  const int n0s = w * 48;
  f32x4 s_acc[4][3];
#pragma unroll
  for (int mt = 0; mt < 4; mt++)
#pragma unroll
    for (int nt = 0; nt < 3; nt++) s_acc[mt][nt] = (f32x4){0.f, 0.f, 0.f, 0.f};
#pragma unroll
  for (int nt = 0; nt < 3; nt++)
#pragma unroll
    for (int ks = 0; ks < 2; ks++) {
      bf16x8 bk =
          *(const bf16x8*)&KP_s[(n0s + nt * 16 + fm) * KSTR + ks * 32 + quad * 8];
#pragma unroll
      for (int mt = 0; mt < 4; mt++) s_acc[mt][nt] = MFMA(aq[mt][ks], bk, s_acc[mt][nt]);
    }

  // mask (REPLACE, not add) + per-row max
  float rm[4][4];
#pragma unroll
  for (int mt = 0; mt < 4; mt++)
#pragma unroll
    for (int r = 0; r < 4; r++) rm[mt][r] = -1e30f;
#pragma unroll
  for (int mt = 0; mt < 4; mt++)
#pragma unroll
    for (int nt = 0; nt < 3; nt++) {
      int jj = n0s + nt * 16 + fm;
      int jg = j0 + jj;
#pragma unroll
      for (int r = 0; r < 4; r++) {
        int ii = mt * 16 + quad * 4 + r;
        bool ok = (jj >= ii) && (jj <= ii + 128) && (jg >= 0) && (jg < 2048);
        float sv = ok ? s_acc[mt][nt][r] : -1e30f;
        s_acc[mt][nt][r] = sv;
        rm[mt][r] = fmaxf(rm[mt][r], sv);
      }
    }
  // reduce max over the 16-lane col group, then cross-wave via LDS
#pragma unroll
  for (int off = 1; off < 16; off <<= 1)
#pragma unroll
    for (int mt = 0; mt < 4; mt++)
#pragma unroll
      for (int r = 0; r < 4; r++)
        rm[mt][r] = fmaxf(rm[mt][r], __shfl_xor(rm[mt][r], off));
  if (fm == 0)
#pragma unroll
    for (int mt = 0; mt < 4; mt++)
#pragma unroll
      for (int r = 0; r < 4; r++)
        redm[w * 64 + mt * 16 + quad * 4 + r] = rm[mt][r];
  __syncthreads();
  float fmx[4][4];
#pragma unroll
  for (int mt = 0; mt < 4; mt++)
#pragma unroll
    for (int r = 0; r < 4; r++) {
      int row = mt * 16 + quad * 4 + r;
      fmx[mt][r] = fmaxf(fmaxf(redm[row], redm[64 + row]),
                         fmaxf(redm[128 + row], redm[192 + row]));
    }
  // exp + row sum (masked entries underflow to exactly 0)
  float rs[4][4];
#pragma unroll
  for (int mt = 0; mt < 4; mt++)
#pragma unroll
    for (int r = 0; r < 4; r++) rs[mt][r] = 0.f;
#pragma unroll
  for (int mt = 0; mt < 4; mt++)
#pragma unroll
    for (int nt = 0; nt < 3; nt++)
#pragma unroll
      for (int r = 0; r < 4; r++) {
        float e = __expf(s_acc[mt][nt][r] - fmx[mt][r]);
        s_acc[mt][nt][r] = e;
        rs[mt][r] += e;
      }
#pragma unroll
  for (int off = 1; off < 16; off <<= 1)
#pragma unroll
    for (int mt = 0; mt < 4; mt++)
#pragma unroll
      for (int r = 0; r < 4; r++) rs[mt][r] += __shfl_xor(rs[mt][r], off);
  if (fm == 0)
#pragma unroll
    for (int mt = 0; mt < 4; mt++)
#pragma unroll
      for (int r = 0; r < 4; r++)
        reds[w * 64 + mt * 16 + quad * 4 + r] = rs[mt][r];
  __syncthreads();  // also guarantees all K_lds reads done before P overwrites
  float inv[4][4];
#pragma unroll
  for (int mt = 0; mt < 4; mt++)
#pragma unroll
    for (int r = 0; r < 4; r++) {
      int row = mt * 16 + quad * 4 + r;
      inv[mt][r] =
          1.0f / (reds[row] + reds[64 + row] + reds[128 + row] + reds[192 + row]);
    }
  // write P (bf16) into KP_s region with stride VSTR (C layout -> memory)
#pragma unroll
  for (int mt = 0; mt < 4; mt++)
#pragma unroll
    for (int nt = 0; nt < 3; nt++) {
      int col = n0s + nt * 16 + fm;
#pragma unroll
      for (int r = 0; r < 4; r++) {
        int row = mt * 16 + quad * 4 + r;
        KP_s[row * VSTR + col] = f2bf(s_acc[mt][nt][r] * inv[mt][r]);
      }
    }
  __syncthreads();

  // ctx = P @ V ; wave covers dh-cols [w*16, w*16+16)
  const int n0v = w * 16;
  f32x4 o_acc[4];
#pragma unroll
  for (int mt = 0; mt < 4; mt++) o_acc[mt] = (f32x4){0.f, 0.f, 0.f, 0.f};
#pragma unroll
  for (int ks = 0; ks < 6; ks++) {
    bf16x8 bv = *(const bf16x8*)&Vt_s[(n0v + fm) * VSTR + ks * 32 + quad * 8];
#pragma unroll
    for (int mt = 0; mt < 4; mt++) {
      bf16x8 ap = *(const bf16x8*)&KP_s[(mt * 16 + fm) * VSTR + ks * 32 + quad * 8];
      o_acc[mt] = MFMA(ap, bv, o_acc[mt]);
    }
  }
  // write ctx split hi/lo [B*T, 512]
  const int bb = bh >> 3, h = bh & 7;
#pragma unroll
  for (int mt = 0; mt < 4; mt++)
#pragma unroll
    for (int r = 0; r < 4; r++) {
      int t = q0 + mt * 16 + quad * 4 + r;
      int c = h * 64 + n0v + fm;
      float v = o_acc[mt][r];
      unsigned short hv = f2bf(v);
      size_t o = ((size_t)(bb * 2048 + t)) * 512 + c;
      ctx_hi[o] = hv;
      ctx_lo[o] = f2bf(v - bf2f(hv));
    }
}

// ---------------------------------------------------------------------------
extern "C" void kernel_launch(void* const* d_in, const int* in_sizes, int n_in,
                              void* d_out, int out_size, void* d_ws, size_t ws_size,
                              hipStream_t stream) {
  const float* x = (const float*)d_in[0];
  const float* w_in = (const float*)d_in[1];
  const float* b_in = (const float*)d_in[2];
  const float* w_out = (const float*)d_in[3];
  const float* b_out = (const float*)d_in[4];
  float* out = (float*)d_out;

  uint8_t* ws = (uint8_t*)d_ws;
  unsigned short* xT_hi = (unsigned short*)(ws + 0);           // 4 MiB
  unsigned short* xT_lo = (unsigned short*)(ws + 4194304);     // 4 MiB
  unsigned short* wih   = (unsigned short*)(ws + 8388608);     // 1.5 MiB
  unsigned short* woh   = (unsigned short*)(ws + 9961472);     // 0.5 MiB
  unsigned short* Qs    = (unsigned short*)(ws + 12582912);    // 4 MiB
  unsigned short* Kk    = (unsigned short*)(ws + 16777216);    // 4 MiB
  unsigned short* Vv    = (unsigned short*)(ws + 20971520);    // 4 MiB
  unsigned short* ctxh  = (unsigned short*)(ws + 25165824);    // 4 MiB
  unsigned short* ctxl  = (unsigned short*)(ws + 29360128);    // 4 MiB

  k_prep<<<dim3(64, 17, 2), 256, 0, stream>>>(x, w_in, w_out, xT_hi, xT_lo,
                                              wih, woh);
  k_gemm_qkv<<<dim3(12, 32), 256, 0, stream>>>(xT_hi, xT_lo, wih, b_in,
                                               Qs, Kk, Vv);
  k_attention<<<dim3(32, 16), 256, 0, stream>>>(Qs, Kk, Vv, ctxh, ctxl);
  k_gemm_out<<<dim3(4, 64), 256, 0, stream>>>(ctxh, ctxl, woh, b_out, x, out);
}

// Round 4
// 123.735 us; speedup vs baseline: 1.3018x; 1.0195x over previous
//
#include <hip/hip_runtime.h>
#include <stdint.h>

// Encoder: B=2,E=512,T=2048,H=8,dh=64, local window |i-j|<=64
// R4: XCD-aware block swizzle on both GEMMs. With K=512 the A-matrix is
//     re-read once per n-tile (12x / 4x); un-swizzled that traffic goes to
//     L3 (~340 MB, invisible in FETCH_SIZE). Swizzle gives each XCD a
//     4(8) m-tile slab x all n-tiles: working set 3.5(1.5) MB fits the 4 MB
//     per-XCD L2, all 48(32) blocks co-resident. Attention/prep unchanged.

#define DEVI __device__ __forceinline__

typedef __attribute__((ext_vector_type(8))) short bf16x8;   // 8 bf16 in 4 VGPRs
typedef __attribute__((ext_vector_type(4))) float f32x4;

DEVI unsigned short f2bf(float f) {               // RNE float->bf16
  unsigned u = __float_as_uint(f);
  u += 0x7fffu + ((u >> 16) & 1u);
  return (unsigned short)(u >> 16);
}
DEVI float bf2f(unsigned short h) { return __uint_as_float(((unsigned)h) << 16); }

#define GLL16(gp, lp)                                                          \
  __builtin_amdgcn_global_load_lds(                                            \
      (const __attribute__((address_space(1))) void*)(gp),                     \
      (__attribute__((address_space(3))) void*)(lp), 16, 0, 0)

#define MFMA(a, b, c) __builtin_amdgcn_mfma_f32_16x16x32_bf16((a), (b), (c), 0, 0, 0)

// ---------------------------------------------------------------------------
// K0: blockIdx.y<16: x[B,E,T] fp32 -> xT[B*T,512] split bf16 hi/lo (transpose)
//     blockIdx.y==16: w_in/w_out fp32 -> bf16 hi (128 rider blocks)
__global__ __launch_bounds__(256) void k_prep(
    const float* __restrict__ x, const float* __restrict__ w_in,
    const float* __restrict__ w_out, unsigned short* __restrict__ xh,
    unsigned short* __restrict__ xl, unsigned short* __restrict__ wih,
    unsigned short* __restrict__ woh) {
  const int tid = threadIdx.x;
  if (blockIdx.y == 16) {  // weight convert rider: 128 blocks x 8192 elems
    int cb = (blockIdx.z << 6) | blockIdx.x;
    const float* src;
    unsigned short* dst;
    int base;
    if (cb < 96) {        // 96*8192 = 786432 = w_in exactly
      src = w_in; dst = wih; base = cb * 8192;
    } else {              // 32*8192 = 262144 = w_out exactly
      src = w_out; dst = woh; base = (cb - 96) * 8192;
    }
#pragma unroll
    for (int k = 0; k < 8; k++) {
      int idx = base + (k * 256 + tid) * 4;
      float4 v = *(const float4*)&src[idx];
      ushort4 o;
      o.x = f2bf(v.x); o.y = f2bf(v.y); o.z = f2bf(v.z); o.w = f2bf(v.w);
      *(ushort4*)&dst[idx] = o;
    }
    return;
  }
  __shared__ float tile[32][33];
  const int b = blockIdx.z, e0 = blockIdx.y * 32, t0 = blockIdx.x * 32;
  const int j = tid & 31, i = tid >> 5;  // i: 0..7
#pragma unroll
  for (int rr = 0; rr < 4; rr++) {
    int e = e0 + i + rr * 8;
    tile[i + rr * 8][j] = x[((size_t)b * 512 + e) * 2048 + t0 + j];  // coalesced t
  }
  __syncthreads();
#pragma unroll
  for (int rr = 0; rr < 4; rr++) {
    int t = t0 + i + rr * 8;
    float v = tile[j][i + rr * 8];
    size_t o = ((size_t)b * 2048 + t) * 512 + e0 + j;  // coalesced e
    unsigned short hv = f2bf(v);
    xh[o] = hv;
    xl[o] = f2bf(v - bf2f(hv));
  }
}

// ---------------------------------------------------------------------------
// QKV GEMM: C[m,n] = sum_k (Ah+Al)[m,k]*Bh[n,k] + bias[n], 128x128 tile, BK=32.
// Grid: 384 linear, XCD-swizzled: xcd owns m-tiles [xcd*4, xcd*4+4) x all 12 n.
// Epilogue scatters into Q(*0.125)/K/V [B,H,T,64] bf16.
__global__ __launch_bounds__(256) void k_gemm_qkv(
    const unsigned short* __restrict__ Ahg, const unsigned short* __restrict__ Alg,
    const unsigned short* __restrict__ Bhg, const float* __restrict__ bias,
    unsigned short* __restrict__ Qs, unsigned short* __restrict__ Kks,
    unsigned short* __restrict__ Vvs) {
  const int KD = 512;
  __shared__ __align__(16) unsigned short Ah_s[128 * 32];
  __shared__ __align__(16) unsigned short Al_s[128 * 32];
  __shared__ __align__(16) unsigned short Bh_s[128 * 32];
  const int tid = threadIdx.x, lane = tid & 63, w = tid >> 6;
  // XCD swizzle: dispatch heuristic xcd = bid%8; 48 blocks/XCD = 4m x 12n slab
  const int bid = blockIdx.x;
  const int xcd = bid & 7, j5 = bid >> 3;
  const int m0 = (xcd * 4 + j5 / 12) * 128, n0 = (j5 % 12) * 128;
  const int wm = (w >> 1) * 64, wn = (w & 1) * 64;

  f32x4 acc[4][4];
#pragma unroll
  for (int i = 0; i < 4; i++)
#pragma unroll
    for (int j = 0; j < 4; j++) acc[i][j] = (f32x4){0.f, 0.f, 0.f, 0.f};

  const int srw = lane >> 2, sc = (lane & 3) * 8;
  const size_t b0 = (size_t)(n0 + w * 32 + srw) * KD + sc;
  const size_t b1 = b0 + (size_t)16 * KD;
  unsigned short* lB0 = &Bh_s[(w * 32) * 32];
  unsigned short* lB1 = &Bh_s[(w * 32 + 16) * 32];
  const size_t a0 = (size_t)(m0 + w * 32 + srw) * KD + sc;
  const size_t a1 = a0 + (size_t)16 * KD;
  unsigned short* lAh0 = &Ah_s[(w * 32) * 32];
  unsigned short* lAh1 = &Ah_s[(w * 32 + 16) * 32];
  unsigned short* lAl0 = &Al_s[(w * 32) * 32];
  unsigned short* lAl1 = &Al_s[(w * 32 + 16) * 32];

  const int fm = lane & 15, fq = (lane >> 4) * 8;

  for (int k0 = 0; k0 < KD; k0 += 32) {
    __syncthreads();
    GLL16(Ahg + a0 + k0, lAh0);
    GLL16(Ahg + a1 + k0, lAh1);
    GLL16(Alg + a0 + k0, lAl0);
    GLL16(Alg + a1 + k0, lAl1);
    GLL16(Bhg + b0 + k0, lB0);
    GLL16(Bhg + b1 + k0, lB1);
    __builtin_amdgcn_s_waitcnt(0);
    __syncthreads();

    bf16x8 ah[4], al[4], bh[4];
#pragma unroll
    for (int i = 0; i < 4; i++) {
      ah[i] = *(const bf16x8*)&Ah_s[(wm + i * 16 + fm) * 32 + fq];
      al[i] = *(const bf16x8*)&Al_s[(wm + i * 16 + fm) * 32 + fq];
      bh[i] = *(const bf16x8*)&Bh_s[(wn + i * 16 + fm) * 32 + fq];
    }
#pragma unroll
    for (int i = 0; i < 4; i++)
#pragma unroll
      for (int j = 0; j < 4; j++) {
        acc[i][j] = MFMA(ah[i], bh[j], acc[i][j]);
        acc[i][j] = MFMA(al[i], bh[j], acc[i][j]);
      }
  }

  // epilogue: C/D layout col=lane&15, row=quad*4+r  [m89-verified]
  const int quad = lane >> 4;
#pragma unroll
  for (int i = 0; i < 4; i++)
#pragma unroll
    for (int j = 0; j < 4; j++) {
      int gn = n0 + wn + j * 16 + fm;
      float bv = bias[gn];
      int sec = gn >> 9, cc = gn & 511;
      int h = cc >> 6, d = cc & 63;
      unsigned short* dst = sec == 0 ? Qs : (sec == 1 ? Kks : Vvs);
      float mul = sec == 0 ? 0.125f : 1.0f;  // 1/sqrt(64), exact
#pragma unroll
      for (int r = 0; r < 4; r++) {
        int gm = m0 + wm + i * 16 + quad * 4 + r;
        int bb = gm >> 11, t = gm & 2047;
        float v = (acc[i][j][r] + bv) * mul;
        dst[(((size_t)(bb * 8 + h)) * 2048 + t) * 64 + d] = f2bf(v);
      }
    }
}

// ---------------------------------------------------------------------------
// Out-proj GEMM fused with final transpose * x + relu.
// C[m,n] = sum_k (Ah+Al)[m,k]*Bh[n,k] + bias[n]; tile 64m x 128n.
// Grid: 256 linear, XCD-swizzled: xcd owns m-tiles [xcd*8, xcd*8+8) x all 4 n.
// Epilogue: LDS transpose -> out[b,e,t] = relu(C[b,t,e] * x[b,e,t]).
__global__ __launch_bounds__(256) void k_gemm_out(
    const unsigned short* __restrict__ Ahg, const unsigned short* __restrict__ Alg,
    const unsigned short* __restrict__ Bhg, const float* __restrict__ bias,
    const float* __restrict__ x, float* __restrict__ out) {
  const int KD = 512;
  __shared__ __align__(16) union {
    struct {
      unsigned short Ah[64 * 32];
      unsigned short Al[64 * 32];
      unsigned short Bh[128 * 32];
    } st;                       // 16 KB staging
    float tile[64][129];        // 32.25 KB epilogue transpose
  } u;
  const int tid = threadIdx.x, lane = tid & 63, w = tid >> 6;
  // XCD swizzle: 32 blocks/XCD = 8m x 4n slab (A 1 MB + B 0.5 MB in L2)
  const int bid = blockIdx.x;
  const int xcd = bid & 7, j5 = bid >> 3;
  const int m0 = (xcd * 8 + (j5 >> 2)) * 64, n0 = (j5 & 3) * 128;
  const int wm = (w >> 1) * 32, wn = (w & 1) * 64;

  f32x4 acc[2][4];
#pragma unroll
  for (int i = 0; i < 2; i++)
#pragma unroll
    for (int j = 0; j < 4; j++) acc[i][j] = (f32x4){0.f, 0.f, 0.f, 0.f};

  const int srw = lane >> 2, sc = (lane & 3) * 8;
  const size_t b0 = (size_t)(n0 + w * 32 + srw) * KD + sc;
  const size_t b1 = b0 + (size_t)16 * KD;
  const size_t a0 = (size_t)(m0 + w * 16 + srw) * KD + sc;
  unsigned short* lB0 = &u.st.Bh[(w * 32) * 32];
  unsigned short* lB1 = &u.st.Bh[(w * 32 + 16) * 32];
  unsigned short* lAh0 = &u.st.Ah[(w * 16) * 32];
  unsigned short* lAl0 = &u.st.Al[(w * 16) * 32];

  const int fm = lane & 15, fq = (lane >> 4) * 8;

  for (int k0 = 0; k0 < KD; k0 += 32) {
    __syncthreads();
    GLL16(Ahg + a0 + k0, lAh0);
    GLL16(Alg + a0 + k0, lAl0);
    GLL16(Bhg + b0 + k0, lB0);
    GLL16(Bhg + b1 + k0, lB1);
    __builtin_amdgcn_s_waitcnt(0);
    __syncthreads();

    bf16x8 ah[2], al[2], bh[4];
#pragma unroll
    for (int i = 0; i < 2; i++) {
      ah[i] = *(const bf16x8*)&u.st.Ah[(wm + i * 16 + fm) * 32 + fq];
      al[i] = *(const bf16x8*)&u.st.Al[(wm + i * 16 + fm) * 32 + fq];
    }
#pragma unroll
    for (int j = 0; j < 4; j++)
      bh[j] = *(const bf16x8*)&u.st.Bh[(wn + j * 16 + fm) * 32 + fq];
#pragma unroll
    for (int i = 0; i < 2; i++)
#pragma unroll
      for (int j = 0; j < 4; j++) {
        acc[i][j] = MFMA(ah[i], bh[j], acc[i][j]);
        acc[i][j] = MFMA(al[i], bh[j], acc[i][j]);
      }
  }

  __syncthreads();  // all frag reads done before tile overwrites staging
  // write acc+bias into transpose tile: tile[t_local][e_local]
  const int quad = lane >> 4;
#pragma unroll
  for (int i = 0; i < 2; i++)
#pragma unroll
    for (int j = 0; j < 4; j++) {
      int ln = wn + j * 16 + fm;
      float bv = bias[n0 + ln];
#pragma unroll
      for (int r = 0; r < 4; r++) {
        int lm = wm + i * 16 + quad * 4 + r;
        u.tile[lm][ln] = acc[i][j][r] + bv;
      }
    }
  __syncthreads();

  // out[b,e,t] = relu(tile[t][e] * x[b,e,t]); coalesced along t
  const int bb = m0 >> 11, t0 = m0 & 2047;
  const int tt = tid & 63, e0w = tid >> 6;
#pragma unroll
  for (int k = 0; k < 32; k++) {
    int ee = e0w + k * 4;
    size_t o = ((size_t)bb * 512 + n0 + ee) * 2048 + t0 + tt;
    float v = u.tile[tt][ee] * x[o];
    out[o] = fmaxf(v, 0.f);
  }
}

// ---------------------------------------------------------------------------
// K2: local attention. Block = (b,h, 64 queries). Window = 192 keys.
#define KSTR 88   // K_lds row stride (bf16): 176B, 2-way-free b128 reads
#define VSTR 216  // Vt/P row stride (bf16): 432B, 2-way-free b128 reads
__global__ __launch_bounds__(256) void k_attention(
    const unsigned short* __restrict__ Qs, const unsigned short* __restrict__ Kks,
    const unsigned short* __restrict__ Vvs, unsigned short* __restrict__ ctx_hi,
    unsigned short* __restrict__ ctx_lo) {
  __shared__ __align__(16) unsigned short KP_s[192 * KSTR];  // K, later P (64 x VSTR)
  __shared__ __align__(16) unsigned short Vt_s[64 * VSTR];   // V^T [dh][key]
  __shared__ float redm[4 * 64];
  __shared__ float reds[4 * 64];

  const int tid = threadIdx.x, lane = tid & 63, w = tid >> 6;
  const int q0 = blockIdx.x * 64;
  const int bh = blockIdx.y;
  const int j0 = q0 - 64;
  const size_t base = (size_t)bh * 2048 * 64;

  // stage K rows (clamped; garbage rows are masked before softmax)
  for (int idx = tid; idx < 192 * 8; idx += 256) {
    int r = idx >> 3, c = idx & 7;
    int j = j0 + r;
    j = j < 0 ? 0 : (j > 2047 ? 2047 : j);
    uint4 v = *(const uint4*)&Kks[base + (size_t)j * 64 + c * 8];
    *(uint4*)&KP_s[r * KSTR + c * 8] = v;
  }
  // stage V transposed: vector global load (8 shorts) + LDS transpose scatter
  for (int idx = tid; idx < 192 * 8; idx += 256) {
    int r = idx >> 3, c8 = (idx & 7) * 8;
    int j = j0 + r;
    uint4 v;
    if (j >= 0 && j < 2048)
      v = *(const uint4*)&Vvs[base + (size_t)j * 64 + c8];
    else
      v = (uint4){0u, 0u, 0u, 0u};  // OOB rows ZERO (0*garbage hazard)
    const unsigned short* e = (const unsigned short*)&v;
#pragma unroll
    for (int uu = 0; uu < 8; uu++) Vt_s[(c8 + uu) * VSTR + r] = e[uu];
  }

  // Q fragments straight from global (A layout: m=lane&15, k=quad*8+j)
  const int fm = lane & 15, quad = lane >> 4;
  bf16x8 aq[4][2];
#pragma unroll
  for (int mt = 0; mt < 4; mt++)
#pragma unroll
    for (int ks = 0; ks < 2; ks++)
      aq[mt][ks] = *(const bf16x8*)&Qs[base + (size_t)(q0 + mt * 16 + fm) * 64 +
                                       ks * 32 + quad * 8];
  __syncthreads();

  // S = Qs @ K^T ; wave covers key-cols [w*48, w*48+48)
  const int n0s = w * 48;
  f32x4 s_acc[4][3];
#pragma unroll
  for (int mt = 0; mt < 4; mt++)
#pragma unroll
    for (int nt = 0; nt < 3; nt++) s_acc[mt][nt] = (f32x4){0.f, 0.f, 0.f, 0.f};
#pragma unroll
  for (int nt = 0; nt < 3; nt++)
#pragma unroll
    for (int ks = 0; ks < 2; ks++) {
      bf16x8 bk =
          *(const bf16x8*)&KP_s[(n0s + nt * 16 + fm) * KSTR + ks * 32 + quad * 8];
#pragma unroll
      for (int mt = 0; mt < 4; mt++) s_acc[mt][nt] = MFMA(aq[mt][ks], bk, s_acc[mt][nt]);
    }

  // mask (REPLACE, not add) + per-row max
  float rm[4][4];
#pragma unroll
  for (int mt = 0; mt < 4; mt++)
#pragma unroll
    for (int r = 0; r < 4; r++) rm[mt][r] = -1e30f;
#pragma unroll
  for (int mt = 0; mt < 4; mt++)
#pragma unroll
    for (int nt = 0; nt < 3; nt++) {
      int jj = n0s + nt * 16 + fm;
      int jg = j0 + jj;
#pragma unroll
      for (int r = 0; r < 4; r++) {
        int ii = mt * 16 + quad * 4 + r;
        bool ok = (jj >= ii) && (jj <= ii + 128) && (jg >= 0) && (jg < 2048);
        float sv = ok ? s_acc[mt][nt][r] : -1e30f;
        s_acc[mt][nt][r] = sv;
        rm[mt][r] = fmaxf(rm[mt][r], sv);
      }
    }
  // reduce max over the 16-lane col group, then cross-wave via LDS
#pragma unroll
  for (int off = 1; off < 16; off <<= 1)
#pragma unroll
    for (int mt = 0; mt < 4; mt++)
#pragma unroll
      for (int r = 0; r < 4; r++)
        rm[mt][r] = fmaxf(rm[mt][r], __shfl_xor(rm[mt][r], off));
  if (fm == 0)
#pragma unroll
    for (int mt = 0; mt < 4; mt++)
#pragma unroll
      for (int r = 0; r < 4; r++)
        redm[w * 64 + mt * 16 + quad * 4 + r] = rm[mt][r];
  __syncthreads();
  float fmx[4][4];
#pragma unroll
  for (int mt = 0; mt < 4; mt++)
#pragma unroll
    for (int r = 0; r < 4; r++) {
      int row = mt * 16 + quad * 4 + r;
      fmx[mt][r] = fmaxf(fmaxf(redm[row], redm[64 + row]),
                         fmaxf(redm[128 + row], redm[192 + row]));
    }
  // exp + row sum (masked entries underflow to exactly 0)
  float rs[4][4];
#pragma unroll
  for (int mt = 0; mt < 4; mt++)
#pragma unroll
    for (int r = 0; r < 4; r++) rs[mt][r] = 0.f;
#pragma unroll
  for (int mt = 0; mt < 4; mt++)
#pragma unroll
    for (int nt = 0; nt < 3; nt++)
#pragma unroll
      for (int r = 0; r < 4; r++) {
        float e = __expf(s_acc[mt][nt][r] - fmx[mt][r]);
        s_acc[mt][nt][r] = e;
        rs[mt][r] += e;
      }
#pragma unroll
  for (int off = 1; off < 16; off <<= 1)
#pragma unroll
    for (int mt = 0; mt < 4; mt++)
#pragma unroll
      for (int r = 0; r < 4; r++) rs[mt][r] += __shfl_xor(rs[mt][r], off);
  if (fm == 0)
#pragma unroll
    for (int mt = 0; mt < 4; mt++)
#pragma unroll
      for (int r = 0; r < 4; r++)
        reds[w * 64 + mt * 16 + quad * 4 + r] = rs[mt][r];
  __syncthreads();  // also guarantees all K_lds reads done before P overwrites
  float inv[4][4];
#pragma unroll
  for (int mt = 0; mt < 4; mt++)
#pragma unroll
    for (int r = 0; r < 4; r++) {
      int row = mt * 16 + quad * 4 + r;
      inv[mt][r] =
          1.0f / (reds[row] + reds[64 + row] + reds[128 + row] + reds[192 + row]);
    }
  // write P (bf16) into KP_s region with stride VSTR (C layout -> memory)
#pragma unroll
  for (int mt = 0; mt < 4; mt++)
#pragma unroll
    for (int nt = 0; nt < 3; nt++) {
      int col = n0s + nt * 16 + fm;
#pragma unroll
      for (int r = 0; r < 4; r++) {
        int row = mt * 16 + quad * 4 + r;
        KP_s[row * VSTR + col] = f2bf(s_acc[mt][nt][r] * inv[mt][r]);
      }
    }
  __syncthreads();

  // ctx = P @ V ; wave covers dh-cols [w*16, w*16+16)
  const int n0v = w * 16;
  f32x4 o_acc[4];
#pragma unroll
  for (int mt = 0; mt < 4; mt++) o_acc[mt] = (f32x4){0.f, 0.f, 0.f, 0.f};
#pragma unroll
  for (int ks = 0; ks < 6; ks++) {
    bf16x8 bv = *(const bf16x8*)&Vt_s[(n0v + fm) * VSTR + ks * 32 + quad * 8];
#pragma unroll
    for (int mt = 0; mt < 4; mt++) {
      bf16x8 ap = *(const bf16x8*)&KP_s[(mt * 16 + fm) * VSTR + ks * 32 + quad * 8];
      o_acc[mt] = MFMA(ap, bv, o_acc[mt]);
    }
  }
  // write ctx split hi/lo [B*T, 512]
  const int bb = bh >> 3, h = bh & 7;
#pragma unroll
  for (int mt = 0; mt < 4; mt++)
#pragma unroll
    for (int r = 0; r < 4; r++) {
      int t = q0 + mt * 16 + quad * 4 + r;
      int c = h * 64 + n0v + fm;
      float v = o_acc[mt][r];
      unsigned short hv = f2bf(v);
      size_t o = ((size_t)(bb * 2048 + t)) * 512 + c;
      ctx_hi[o] = hv;
      ctx_lo[o] = f2bf(v - bf2f(hv));
    }
}

// ---------------------------------------------------------------------------
extern "C" void kernel_launch(void* const* d_in, const int* in_sizes, int n_in,
                              void* d_out, int out_size, void* d_ws, size_t ws_size,
                              hipStream_t stream) {
  const float* x = (const float*)d_in[0];
  const float* w_in = (const float*)d_in[1];
  const float* b_in = (const float*)d_in[2];
  const float* w_out = (const float*)d_in[3];
  const float* b_out = (const float*)d_in[4];
  float* out = (float*)d_out;

  uint8_t* ws = (uint8_t*)d_ws;
  unsigned short* xT_hi = (unsigned short*)(ws + 0);           // 4 MiB
  unsigned short* xT_lo = (unsigned short*)(ws + 4194304);     // 4 MiB
  unsigned short* wih   = (unsigned short*)(ws + 8388608);     // 1.5 MiB
  unsigned short* woh   = (unsigned short*)(ws + 9961472);     // 0.5 MiB
  unsigned short* Qs    = (unsigned short*)(ws + 12582912);    // 4 MiB
  unsigned short* Kk    = (unsigned short*)(ws + 16777216);    // 4 MiB
  unsigned short* Vv    = (unsigned short*)(ws + 20971520);    // 4 MiB
  unsigned short* ctxh  = (unsigned short*)(ws + 25165824);    // 4 MiB
  unsigned short* ctxl  = (unsigned short*)(ws + 29360128);    // 4 MiB

  k_prep<<<dim3(64, 17, 2), 256, 0, stream>>>(x, w_in, w_out, xT_hi, xT_lo,
                                              wih, woh);
  k_gemm_qkv<<<384, 256, 0, stream>>>(xT_hi, xT_lo, wih, b_in, Qs, Kk, Vv);
  k_attention<<<dim3(32, 16), 256, 0, stream>>>(Qs, Kk, Vv, ctxh, ctxl);
  k_gemm_out<<<256, 256, 0, stream>>>(ctxh, ctxl, woh, b_out, x, out);
}

// Round 5
// 117.426 us; speedup vs baseline: 1.3717x; 1.0537x over previous
//
#include <hip/hip_runtime.h>
#include <stdint.h>

// Encoder: B=2,E=512,T=2048,H=8,dh=64, local window |i-j|<=64
// R5: drop A-lo pass in QKV GEMM (error budget: R1->R2 A/B measured +0.004
//     per dropped lo-term; predicted absmax ~0.02 < 0.0406 threshold).
//     QKV K-iter: 6->4 GLL16, 32->16 MFMA. prep no longer writes xT_lo.
//     ctx hi/lo split retained in out-proj. Attention/out unchanged.

#define DEVI __device__ __forceinline__

typedef __attribute__((ext_vector_type(8))) short bf16x8;   // 8 bf16 in 4 VGPRs
typedef __attribute__((ext_vector_type(4))) float f32x4;

DEVI unsigned short f2bf(float f) {               // RNE float->bf16
  unsigned u = __float_as_uint(f);
  u += 0x7fffu + ((u >> 16) & 1u);
  return (unsigned short)(u >> 16);
}
DEVI float bf2f(unsigned short h) { return __uint_as_float(((unsigned)h) << 16); }

#define GLL16(gp, lp)                                                          \
  __builtin_amdgcn_global_load_lds(                                            \
      (const __attribute__((address_space(1))) void*)(gp),                     \
      (__attribute__((address_space(3))) void*)(lp), 16, 0, 0)

#define MFMA(a, b, c) __builtin_amdgcn_mfma_f32_16x16x32_bf16((a), (b), (c), 0, 0, 0)

// ---------------------------------------------------------------------------
// K0: blockIdx.y<16: x[B,E,T] fp32 -> xT[B*T,512] bf16 (transpose)
//     blockIdx.y==16: w_in/w_out fp32 -> bf16 hi (128 rider blocks)
__global__ __launch_bounds__(256) void k_prep(
    const float* __restrict__ x, const float* __restrict__ w_in,
    const float* __restrict__ w_out, unsigned short* __restrict__ xh,
    unsigned short* __restrict__ wih, unsigned short* __restrict__ woh) {
  const int tid = threadIdx.x;
  if (blockIdx.y == 16) {  // weight convert rider: 128 blocks x 8192 elems
    int cb = (blockIdx.z << 6) | blockIdx.x;
    const float* src;
    unsigned short* dst;
    int base;
    if (cb < 96) {        // 96*8192 = 786432 = w_in exactly
      src = w_in; dst = wih; base = cb * 8192;
    } else {              // 32*8192 = 262144 = w_out exactly
      src = w_out; dst = woh; base = (cb - 96) * 8192;
    }
#pragma unroll
    for (int k = 0; k < 8; k++) {
      int idx = base + (k * 256 + tid) * 4;
      float4 v = *(const float4*)&src[idx];
      ushort4 o;
      o.x = f2bf(v.x); o.y = f2bf(v.y); o.z = f2bf(v.z); o.w = f2bf(v.w);
      *(ushort4*)&dst[idx] = o;
    }
    return;
  }
  __shared__ float tile[32][33];
  const int b = blockIdx.z, e0 = blockIdx.y * 32, t0 = blockIdx.x * 32;
  const int j = tid & 31, i = tid >> 5;  // i: 0..7
#pragma unroll
  for (int rr = 0; rr < 4; rr++) {
    int e = e0 + i + rr * 8;
    tile[i + rr * 8][j] = x[((size_t)b * 512 + e) * 2048 + t0 + j];  // coalesced t
  }
  __syncthreads();
#pragma unroll
  for (int rr = 0; rr < 4; rr++) {
    int t = t0 + i + rr * 8;
    float v = tile[j][i + rr * 8];
    size_t o = ((size_t)b * 2048 + t) * 512 + e0 + j;  // coalesced e
    xh[o] = f2bf(v);
  }
}

// ---------------------------------------------------------------------------
// QKV GEMM: C[m,n] = sum_k Ah[m,k]*Bh[n,k] + bias[n], 128x128 tile, BK=32.
// Grid: 384 linear, XCD-swizzled: xcd owns m-tiles [xcd*4, xcd*4+4) x all 12 n.
// Epilogue scatters into Q(*0.125)/K/V [B,H,T,64] bf16.
__global__ __launch_bounds__(256) void k_gemm_qkv(
    const unsigned short* __restrict__ Ahg, const unsigned short* __restrict__ Bhg,
    const float* __restrict__ bias, unsigned short* __restrict__ Qs,
    unsigned short* __restrict__ Kks, unsigned short* __restrict__ Vvs) {
  const int KD = 512;
  __shared__ __align__(16) unsigned short Ah_s[128 * 32];
  __shared__ __align__(16) unsigned short Bh_s[128 * 32];
  const int tid = threadIdx.x, lane = tid & 63, w = tid >> 6;
  // XCD swizzle: dispatch heuristic xcd = bid%8; 48 blocks/XCD = 4m x 12n slab
  const int bid = blockIdx.x;
  const int xcd = bid & 7, j5 = bid >> 3;
  const int m0 = (xcd * 4 + j5 / 12) * 128, n0 = (j5 % 12) * 128;
  const int wm = (w >> 1) * 64, wn = (w & 1) * 64;

  f32x4 acc[4][4];
#pragma unroll
  for (int i = 0; i < 4; i++)
#pragma unroll
    for (int j = 0; j < 4; j++) acc[i][j] = (f32x4){0.f, 0.f, 0.f, 0.f};

  const int srw = lane >> 2, sc = (lane & 3) * 8;
  const size_t b0 = (size_t)(n0 + w * 32 + srw) * KD + sc;
  const size_t b1 = b0 + (size_t)16 * KD;
  unsigned short* lB0 = &Bh_s[(w * 32) * 32];
  unsigned short* lB1 = &Bh_s[(w * 32 + 16) * 32];
  const size_t a0 = (size_t)(m0 + w * 32 + srw) * KD + sc;
  const size_t a1 = a0 + (size_t)16 * KD;
  unsigned short* lAh0 = &Ah_s[(w * 32) * 32];
  unsigned short* lAh1 = &Ah_s[(w * 32 + 16) * 32];

  const int fm = lane & 15, fq = (lane >> 4) * 8;

  for (int k0 = 0; k0 < KD; k0 += 32) {
    __syncthreads();
    GLL16(Ahg + a0 + k0, lAh0);
    GLL16(Ahg + a1 + k0, lAh1);
    GLL16(Bhg + b0 + k0, lB0);
    GLL16(Bhg + b1 + k0, lB1);
    __builtin_amdgcn_s_waitcnt(0);
    __syncthreads();

    bf16x8 ah[4], bh[4];
#pragma unroll
    for (int i = 0; i < 4; i++) {
      ah[i] = *(const bf16x8*)&Ah_s[(wm + i * 16 + fm) * 32 + fq];
      bh[i] = *(const bf16x8*)&Bh_s[(wn + i * 16 + fm) * 32 + fq];
    }
#pragma unroll
    for (int i = 0; i < 4; i++)
#pragma unroll
      for (int j = 0; j < 4; j++)
        acc[i][j] = MFMA(ah[i], bh[j], acc[i][j]);
  }

  // epilogue: C/D layout col=lane&15, row=quad*4+r  [m89-verified]
  const int quad = lane >> 4;
#pragma unroll
  for (int i = 0; i < 4; i++)
#pragma unroll
    for (int j = 0; j < 4; j++) {
      int gn = n0 + wn + j * 16 + fm;
      float bv = bias[gn];
      int sec = gn >> 9, cc = gn & 511;
      int h = cc >> 6, d = cc & 63;
      unsigned short* dst = sec == 0 ? Qs : (sec == 1 ? Kks : Vvs);
      float mul = sec == 0 ? 0.125f : 1.0f;  // 1/sqrt(64), exact
#pragma unroll
      for (int r = 0; r < 4; r++) {
        int gm = m0 + wm + i * 16 + quad * 4 + r;
        int bb = gm >> 11, t = gm & 2047;
        float v = (acc[i][j][r] + bv) * mul;
        dst[(((size_t)(bb * 8 + h)) * 2048 + t) * 64 + d] = f2bf(v);
      }
    }
}

// ---------------------------------------------------------------------------
// Out-proj GEMM fused with final transpose * x + relu.
// C[m,n] = sum_k (Ah+Al)[m,k]*Bh[n,k] + bias[n]; tile 64m x 128n.
// Grid: 256 linear, XCD-swizzled: xcd owns m-tiles [xcd*8, xcd*8+8) x all 4 n.
// Epilogue: LDS transpose -> out[b,e,t] = relu(C[b,t,e] * x[b,e,t]).
__global__ __launch_bounds__(256) void k_gemm_out(
    const unsigned short* __restrict__ Ahg, const unsigned short* __restrict__ Alg,
    const unsigned short* __restrict__ Bhg, const float* __restrict__ bias,
    const float* __restrict__ x, float* __restrict__ out) {
  const int KD = 512;
  __shared__ __align__(16) union {
    struct {
      unsigned short Ah[64 * 32];
      unsigned short Al[64 * 32];
      unsigned short Bh[128 * 32];
    } st;                       // 16 KB staging
    float tile[64][129];        // 32.25 KB epilogue transpose
  } u;
  const int tid = threadIdx.x, lane = tid & 63, w = tid >> 6;
  // XCD swizzle: 32 blocks/XCD = 8m x 4n slab (A 1 MB + B 0.5 MB in L2)
  const int bid = blockIdx.x;
  const int xcd = bid & 7, j5 = bid >> 3;
  const int m0 = (xcd * 8 + (j5 >> 2)) * 64, n0 = (j5 & 3) * 128;
  const int wm = (w >> 1) * 32, wn = (w & 1) * 64;

  f32x4 acc[2][4];
#pragma unroll
  for (int i = 0; i < 2; i++)
#pragma unroll
    for (int j = 0; j < 4; j++) acc[i][j] = (f32x4){0.f, 0.f, 0.f, 0.f};

  const int srw = lane >> 2, sc = (lane & 3) * 8;
  const size_t b0 = (size_t)(n0 + w * 32 + srw) * KD + sc;
  const size_t b1 = b0 + (size_t)16 * KD;
  const size_t a0 = (size_t)(m0 + w * 16 + srw) * KD + sc;
  unsigned short* lB0 = &u.st.Bh[(w * 32) * 32];
  unsigned short* lB1 = &u.st.Bh[(w * 32 + 16) * 32];
  unsigned short* lAh0 = &u.st.Ah[(w * 16) * 32];
  unsigned short* lAl0 = &u.st.Al[(w * 16) * 32];

  const int fm = lane & 15, fq = (lane >> 4) * 8;

  for (int k0 = 0; k0 < KD; k0 += 32) {
    __syncthreads();
    GLL16(Ahg + a0 + k0, lAh0);
    GLL16(Alg + a0 + k0, lAl0);
    GLL16(Bhg + b0 + k0, lB0);
    GLL16(Bhg + b1 + k0, lB1);
    __builtin_amdgcn_s_waitcnt(0);
    __syncthreads();

    bf16x8 ah[2], al[2], bh[4];
#pragma unroll
    for (int i = 0; i < 2; i++) {
      ah[i] = *(const bf16x8*)&u.st.Ah[(wm + i * 16 + fm) * 32 + fq];
      al[i] = *(const bf16x8*)&u.st.Al[(wm + i * 16 + fm) * 32 + fq];
    }
#pragma unroll
    for (int j = 0; j < 4; j++)
      bh[j] = *(const bf16x8*)&u.st.Bh[(wn + j * 16 + fm) * 32 + fq];
#pragma unroll
    for (int i = 0; i < 2; i++)
#pragma unroll
      for (int j = 0; j < 4; j++) {
        acc[i][j] = MFMA(ah[i], bh[j], acc[i][j]);
        acc[i][j] = MFMA(al[i], bh[j], acc[i][j]);
      }
  }

  __syncthreads();  // all frag reads done before tile overwrites staging
  // write acc+bias into transpose tile: tile[t_local][e_local]
  const int quad = lane >> 4;
#pragma unroll
  for (int i = 0; i < 2; i++)
#pragma unroll
    for (int j = 0; j < 4; j++) {
      int ln = wn + j * 16 + fm;
      float bv = bias[n0 + ln];
#pragma unroll
      for (int r = 0; r < 4; r++) {
        int lm = wm + i * 16 + quad * 4 + r;
        u.tile[lm][ln] = acc[i][j][r] + bv;
      }
    }
  __syncthreads();

  // out[b,e,t] = relu(tile[t][e] * x[b,e,t]); coalesced along t
  const int bb = m0 >> 11, t0 = m0 & 2047;
  const int tt = tid & 63, e0w = tid >> 6;
#pragma unroll
  for (int k = 0; k < 32; k++) {
    int ee = e0w + k * 4;
    size_t o = ((size_t)bb * 512 + n0 + ee) * 2048 + t0 + tt;
    float v = u.tile[tt][ee] * x[o];
    out[o] = fmaxf(v, 0.f);
  }
}

// ---------------------------------------------------------------------------
// K2: local attention. Block = (b,h, 64 queries). Window = 192 keys.
#define KSTR 88   // K_lds row stride (bf16): 176B, 2-way-free b128 reads
#define VSTR 216  // Vt/P row stride (bf16): 432B, 2-way-free b128 reads
__global__ __launch_bounds__(256) void k_attention(
    const unsigned short* __restrict__ Qs, const unsigned short* __restrict__ Kks,
    const unsigned short* __restrict__ Vvs, unsigned short* __restrict__ ctx_hi,
    unsigned short* __restrict__ ctx_lo) {
  __shared__ __align__(16) unsigned short KP_s[192 * KSTR];  // K, later P (64 x VSTR)
  __shared__ __align__(16) unsigned short Vt_s[64 * VSTR];   // V^T [dh][key]
  __shared__ float redm[4 * 64];
  __shared__ float reds[4 * 64];

  const int tid = threadIdx.x, lane = tid & 63, w = tid >> 6;
  const int q0 = blockIdx.x * 64;
  const int bh = blockIdx.y;
  const int j0 = q0 - 64;
  const size_t base = (size_t)bh * 2048 * 64;

  // stage K rows (clamped; garbage rows are masked before softmax)
  for (int idx = tid; idx < 192 * 8; idx += 256) {
    int r = idx >> 3, c = idx & 7;
    int j = j0 + r;
    j = j < 0 ? 0 : (j > 2047 ? 2047 : j);
    uint4 v = *(const uint4*)&Kks[base + (size_t)j * 64 + c * 8];
    *(uint4*)&KP_s[r * KSTR + c * 8] = v;
  }
  // stage V transposed: vector global load (8 shorts) + LDS transpose scatter
  for (int idx = tid; idx < 192 * 8; idx += 256) {
    int r = idx >> 3, c8 = (idx & 7) * 8;
    int j = j0 + r;
    uint4 v;
    if (j >= 0 && j < 2048)
      v = *(const uint4*)&Vvs[base + (size_t)j * 64 + c8];
    else
      v = (uint4){0u, 0u, 0u, 0u};  // OOB rows ZERO (0*garbage hazard)
    const unsigned short* e = (const unsigned short*)&v;
#pragma unroll
    for (int uu = 0; uu < 8; uu++) Vt_s[(c8 + uu) * VSTR + r] = e[uu];
  }

  // Q fragments straight from global (A layout: m=lane&15, k=quad*8+j)
  const int fm = lane & 15, quad = lane >> 4;
  bf16x8 aq[4][2];
#pragma unroll
  for (int mt = 0; mt < 4; mt++)
#pragma unroll
    for (int ks = 0; ks < 2; ks++)
      aq[mt][ks] = *(const bf16x8*)&Qs[base + (size_t)(q0 + mt * 16 + fm) * 64 +
                                       ks * 32 + quad * 8];
  __syncthreads();

  // S = Qs @ K^T ; wave covers key-cols [w*48, w*48+48)
  const int n0s = w * 48;
  f32x4 s_acc[4][3];
#pragma unroll
  for (int mt = 0; mt < 4; mt++)
#pragma unroll
    for (int nt = 0; nt < 3; nt++) s_acc[mt][nt] = (f32x4){0.f, 0.f, 0.f, 0.f};
#pragma unroll
  for (int nt = 0; nt < 3; nt++)
#pragma unroll
    for (int ks = 0; ks < 2; ks++) {
      bf16x8 bk =
          *(const bf16x8*)&KP_s[(n0s + nt * 16 + fm) * KSTR + ks * 32 + quad * 8];
#pragma unroll
      for (int mt = 0; mt < 4; mt++) s_acc[mt][nt] = MFMA(aq[mt][ks], bk, s_acc[mt][nt]);
    }

  // mask (REPLACE, not add) + per-row max
  float rm[4][4];
#pragma unroll
  for (int mt = 0; mt < 4; mt++)
#pragma unroll
    for (int r = 0; r < 4; r++) rm[mt][r] = -1e30f;
#pragma unroll
  for (int mt = 0; mt < 4; mt++)
#pragma unroll
    for (int nt = 0; nt < 3; nt++) {
      int jj = n0s + nt * 16 + fm;
      int jg = j0 + jj;
#pragma unroll
      for (int r = 0; r < 4; r++) {
        int ii = mt * 16 + quad * 4 + r;
        bool ok = (jj >= ii) && (jj <= ii + 128) && (jg >= 0) && (jg < 2048);
        float sv = ok ? s_acc[mt][nt][r] : -1e30f;
        s_acc[mt][nt][r] = sv;
        rm[mt][r] = fmaxf(rm[mt][r], sv);
      }
    }
  // reduce max over the 16-lane col group, then cross-wave via LDS
#pragma unroll
  for (int off = 1; off < 16; off <<= 1)
#pragma unroll
    for (int mt = 0; mt < 4; mt++)
#pragma unroll
      for (int r = 0; r < 4; r++)
        rm[mt][r] = fmaxf(rm[mt][r], __shfl_xor(rm[mt][r], off));
  if (fm == 0)
#pragma unroll
    for (int mt = 0; mt < 4; mt++)
#pragma unroll
      for (int r = 0; r < 4; r++)
        redm[w * 64 + mt * 16 + quad * 4 + r] = rm[mt][r];
  __syncthreads();
  float fmx[4][4];
#pragma unroll
  for (int mt = 0; mt < 4; mt++)
#pragma unroll
    for (int r = 0; r < 4; r++) {
      int row = mt * 16 + quad * 4 + r;
      fmx[mt][r] = fmaxf(fmaxf(redm[row], redm[64 + row]),
                         fmaxf(redm[128 + row], redm[192 + row]));
    }
  // exp + row sum (masked entries underflow to exactly 0)
  float rs[4][4];
#pragma unroll
  for (int mt = 0; mt < 4; mt++)
#pragma unroll
    for (int r = 0; r < 4; r++) rs[mt][r] = 0.f;
#pragma unroll
  for (int mt = 0; mt < 4; mt++)
#pragma unroll
    for (int nt = 0; nt < 3; nt++)
#pragma unroll
      for (int r = 0; r < 4; r++) {
        float e = __expf(s_acc[mt][nt][r] - fmx[mt][r]);
        s_acc[mt][nt][r] = e;
        rs[mt][r] += e;
      }
#pragma unroll
  for (int off = 1; off < 16; off <<= 1)
#pragma unroll
    for (int mt = 0; mt < 4; mt++)
#pragma unroll
      for (int r = 0; r < 4; r++) rs[mt][r] += __shfl_xor(rs[mt][r], off);
  if (fm == 0)
#pragma unroll
    for (int mt = 0; mt < 4; mt++)
#pragma unroll
      for (int r = 0; r < 4; r++)
        reds[w * 64 + mt * 16 + quad * 4 + r] = rs[mt][r];
  __syncthreads();  // also guarantees all K_lds reads done before P overwrites
  float inv[4][4];
#pragma unroll
  for (int mt = 0; mt < 4; mt++)
#pragma unroll
    for (int r = 0; r < 4; r++) {
      int row = mt * 16 + quad * 4 + r;
      inv[mt][r] =
          1.0f / (reds[row] + reds[64 + row] + reds[128 + row] + reds[192 + row]);
    }
  // write P (bf16) into KP_s region with stride VSTR (C layout -> memory)
#pragma unroll
  for (int mt = 0; mt < 4; mt++)
#pragma unroll
    for (int nt = 0; nt < 3; nt++) {
      int col = n0s + nt * 16 + fm;
#pragma unroll
      for (int r = 0; r < 4; r++) {
        int row = mt * 16 + quad * 4 + r;
        KP_s[row * VSTR + col] = f2bf(s_acc[mt][nt][r] * inv[mt][r]);
      }
    }
  __syncthreads();

  // ctx = P @ V ; wave covers dh-cols [w*16, w*16+16)
  const int n0v = w * 16;
  f32x4 o_acc[4];
#pragma unroll
  for (int mt = 0; mt < 4; mt++) o_acc[mt] = (f32x4){0.f, 0.f, 0.f, 0.f};
#pragma unroll
  for (int ks = 0; ks < 6; ks++) {
    bf16x8 bv = *(const bf16x8*)&Vt_s[(n0v + fm) * VSTR + ks * 32 + quad * 8];
#pragma unroll
    for (int mt = 0; mt < 4; mt++) {
      bf16x8 ap = *(const bf16x8*)&KP_s[(mt * 16 + fm) * VSTR + ks * 32 + quad * 8];
      o_acc[mt] = MFMA(ap, bv, o_acc[mt]);
    }
  }
  // write ctx split hi/lo [B*T, 512]
  const int bb = bh >> 3, h = bh & 7;
#pragma unroll
  for (int mt = 0; mt < 4; mt++)
#pragma unroll
    for (int r = 0; r < 4; r++) {
      int t = q0 + mt * 16 + quad * 4 + r;
      int c = h * 64 + n0v + fm;
      float v = o_acc[mt][r];
      unsigned short hv = f2bf(v);
      size_t o = ((size_t)(bb * 2048 + t)) * 512 + c;
      ctx_hi[o] = hv;
      ctx_lo[o] = f2bf(v - bf2f(hv));
    }
}

// ---------------------------------------------------------------------------
extern "C" void kernel_launch(void* const* d_in, const int* in_sizes, int n_in,
                              void* d_out, int out_size, void* d_ws, size_t ws_size,
                              hipStream_t stream) {
  const float* x = (const float*)d_in[0];
  const float* w_in = (const float*)d_in[1];
  const float* b_in = (const float*)d_in[2];
  const float* w_out = (const float*)d_in[3];
  const float* b_out = (const float*)d_in[4];
  float* out = (float*)d_out;

  uint8_t* ws = (uint8_t*)d_ws;
  unsigned short* xT_hi = (unsigned short*)(ws + 0);           // 4 MiB
  unsigned short* wih   = (unsigned short*)(ws + 8388608);     // 1.5 MiB
  unsigned short* woh   = (unsigned short*)(ws + 9961472);     // 0.5 MiB
  unsigned short* Qs    = (unsigned short*)(ws + 12582912);    // 4 MiB
  unsigned short* Kk    = (unsigned short*)(ws + 16777216);    // 4 MiB
  unsigned short* Vv    = (unsigned short*)(ws + 20971520);    // 4 MiB
  unsigned short* ctxh  = (unsigned short*)(ws + 25165824);    // 4 MiB
  unsigned short* ctxl  = (unsigned short*)(ws + 29360128);    // 4 MiB

  k_prep<<<dim3(64, 17, 2), 256, 0, stream>>>(x, w_in, w_out, xT_hi, wih, woh);
  k_gemm_qkv<<<384, 256, 0, stream>>>(xT_hi, wih, b_in, Qs, Kk, Vv);
  k_attention<<<dim3(32, 16), 256, 0, stream>>>(Qs, Kk, Vv, ctxh, ctxl);
  k_gemm_out<<<256, 256, 0, stream>>>(ctxh, ctxl, woh, b_out, x, out);
}

// Round 6
// 115.506 us; speedup vs baseline: 1.3945x; 1.0166x over previous
//
#include <hip/hip_runtime.h>
#include <stdint.h>

// Encoder: B=2,E=512,T=2048,H=8,dh=64, local window |i-j|<=64
// R6: (1) drop ctx-lo (out-proj single-pass A; calibrated +0.004 absmax);
//     (2) V stored transposed [B,H,64,2048] by QKV epilogue (packed ushort4
//         stores) -> attention stages V^T with uint4 copies instead of
//         48 scalar ds_write_u16 per thread;
//     (3) out-proj K-iter: 3 GLL16 + 8 MFMA.

#define DEVI __device__ __forceinline__

typedef __attribute__((ext_vector_type(8))) short bf16x8;   // 8 bf16 in 4 VGPRs
typedef __attribute__((ext_vector_type(4))) float f32x4;

DEVI unsigned short f2bf(float f) {               // RNE float->bf16
  unsigned u = __float_as_uint(f);
  u += 0x7fffu + ((u >> 16) & 1u);
  return (unsigned short)(u >> 16);
}
DEVI float bf2f(unsigned short h) { return __uint_as_float(((unsigned)h) << 16); }

#define GLL16(gp, lp)                                                          \
  __builtin_amdgcn_global_load_lds(                                            \
      (const __attribute__((address_space(1))) void*)(gp),                     \
      (__attribute__((address_space(3))) void*)(lp), 16, 0, 0)

#define MFMA(a, b, c) __builtin_amdgcn_mfma_f32_16x16x32_bf16((a), (b), (c), 0, 0, 0)

// ---------------------------------------------------------------------------
// K0: blockIdx.y<16: x[B,E,T] fp32 -> xT[B*T,512] bf16 (transpose)
//     blockIdx.y==16: w_in/w_out fp32 -> bf16 hi (128 rider blocks)
__global__ __launch_bounds__(256) void k_prep(
    const float* __restrict__ x, const float* __restrict__ w_in,
    const float* __restrict__ w_out, unsigned short* __restrict__ xh,
    unsigned short* __restrict__ wih, unsigned short* __restrict__ woh) {
  const int tid = threadIdx.x;
  if (blockIdx.y == 16) {  // weight convert rider: 128 blocks x 8192 elems
    int cb = (blockIdx.z << 6) | blockIdx.x;
    const float* src;
    unsigned short* dst;
    int base;
    if (cb < 96) {        // 96*8192 = 786432 = w_in exactly
      src = w_in; dst = wih; base = cb * 8192;
    } else {              // 32*8192 = 262144 = w_out exactly
      src = w_out; dst = woh; base = (cb - 96) * 8192;
    }
#pragma unroll
    for (int k = 0; k < 8; k++) {
      int idx = base + (k * 256 + tid) * 4;
      float4 v = *(const float4*)&src[idx];
      ushort4 o;
      o.x = f2bf(v.x); o.y = f2bf(v.y); o.z = f2bf(v.z); o.w = f2bf(v.w);
      *(ushort4*)&dst[idx] = o;
    }
    return;
  }
  __shared__ float tile[32][33];
  const int b = blockIdx.z, e0 = blockIdx.y * 32, t0 = blockIdx.x * 32;
  const int j = tid & 31, i = tid >> 5;  // i: 0..7
#pragma unroll
  for (int rr = 0; rr < 4; rr++) {
    int e = e0 + i + rr * 8;
    tile[i + rr * 8][j] = x[((size_t)b * 512 + e) * 2048 + t0 + j];  // coalesced t
  }
  __syncthreads();
#pragma unroll
  for (int rr = 0; rr < 4; rr++) {
    int t = t0 + i + rr * 8;
    float v = tile[j][i + rr * 8];
    size_t o = ((size_t)b * 2048 + t) * 512 + e0 + j;  // coalesced e
    xh[o] = f2bf(v);
  }
}

// ---------------------------------------------------------------------------
// QKV GEMM: C[m,n] = sum_k Ah[m,k]*Bh[n,k] + bias[n], 128x128 tile, BK=32.
// Grid: 384 linear, XCD-swizzled. Epilogue: Q(*0.125)/K -> [B,H,T,64] bf16,
// V -> TRANSPOSED [B,H,64,T] bf16 (packed ushort4, 4 consecutive t/thread).
__global__ __launch_bounds__(256) void k_gemm_qkv(
    const unsigned short* __restrict__ Ahg, const unsigned short* __restrict__ Bhg,
    const float* __restrict__ bias, unsigned short* __restrict__ Qs,
    unsigned short* __restrict__ Kks, unsigned short* __restrict__ VvT) {
  const int KD = 512;
  __shared__ __align__(16) unsigned short Ah_s[128 * 32];
  __shared__ __align__(16) unsigned short Bh_s[128 * 32];
  const int tid = threadIdx.x, lane = tid & 63, w = tid >> 6;
  // XCD swizzle: dispatch heuristic xcd = bid%8; 48 blocks/XCD = 4m x 12n slab
  const int bid = blockIdx.x;
  const int xcd = bid & 7, j5 = bid >> 3;
  const int m0 = (xcd * 4 + j5 / 12) * 128, n0 = (j5 % 12) * 128;
  const int wm = (w >> 1) * 64, wn = (w & 1) * 64;

  f32x4 acc[4][4];
#pragma unroll
  for (int i = 0; i < 4; i++)
#pragma unroll
    for (int j = 0; j < 4; j++) acc[i][j] = (f32x4){0.f, 0.f, 0.f, 0.f};

  const int srw = lane >> 2, sc = (lane & 3) * 8;
  const size_t b0 = (size_t)(n0 + w * 32 + srw) * KD + sc;
  const size_t b1 = b0 + (size_t)16 * KD;
  unsigned short* lB0 = &Bh_s[(w * 32) * 32];
  unsigned short* lB1 = &Bh_s[(w * 32 + 16) * 32];
  const size_t a0 = (size_t)(m0 + w * 32 + srw) * KD + sc;
  const size_t a1 = a0 + (size_t)16 * KD;
  unsigned short* lAh0 = &Ah_s[(w * 32) * 32];
  unsigned short* lAh1 = &Ah_s[(w * 32 + 16) * 32];

  const int fm = lane & 15, fq = (lane >> 4) * 8;

  for (int k0 = 0; k0 < KD; k0 += 32) {
    __syncthreads();
    GLL16(Ahg + a0 + k0, lAh0);
    GLL16(Ahg + a1 + k0, lAh1);
    GLL16(Bhg + b0 + k0, lB0);
    GLL16(Bhg + b1 + k0, lB1);
    __builtin_amdgcn_s_waitcnt(0);
    __syncthreads();

    bf16x8 ah[4], bh[4];
#pragma unroll
    for (int i = 0; i < 4; i++) {
      ah[i] = *(const bf16x8*)&Ah_s[(wm + i * 16 + fm) * 32 + fq];
      bh[i] = *(const bf16x8*)&Bh_s[(wn + i * 16 + fm) * 32 + fq];
    }
#pragma unroll
    for (int i = 0; i < 4; i++)
#pragma unroll
      for (int j = 0; j < 4; j++)
        acc[i][j] = MFMA(ah[i], bh[j], acc[i][j]);
  }

  // epilogue: C/D layout col=lane&15, row=quad*4+r  [m89-verified]
  const int quad = lane >> 4;
#pragma unroll
  for (int i = 0; i < 4; i++)
#pragma unroll
    for (int j = 0; j < 4; j++) {
      int gn = n0 + wn + j * 16 + fm;
      float bv = bias[gn];
      int sec = gn >> 9, cc = gn & 511;
      int h = cc >> 6, d = cc & 63;
      int gm0 = m0 + wm + i * 16 + quad * 4;       // 4-aligned t base
      int bb = gm0 >> 11, t = gm0 & 2047;
      if (sec == 2) {  // V^T [B,H,64,2048]: 4 consecutive t -> one 8B store
        ushort4 pk;
        pk.x = f2bf(acc[i][j][0] + bv);
        pk.y = f2bf(acc[i][j][1] + bv);
        pk.z = f2bf(acc[i][j][2] + bv);
        pk.w = f2bf(acc[i][j][3] + bv);
        *(ushort4*)&VvT[(((size_t)(bb * 8 + h)) * 64 + d) * 2048 + t] = pk;
      } else {
        unsigned short* dst = sec == 0 ? Qs : Kks;
        float mul = sec == 0 ? 0.125f : 1.0f;  // 1/sqrt(64), exact
#pragma unroll
        for (int r = 0; r < 4; r++) {
          float v = (acc[i][j][r] + bv) * mul;
          dst[(((size_t)(bb * 8 + h)) * 2048 + t + r) * 64 + d] = f2bf(v);
        }
      }
    }
}

// ---------------------------------------------------------------------------
// Out-proj GEMM fused with final transpose * x + relu. Single-pass bf16.
// C[m,n] = sum_k Ah[m,k]*Bh[n,k] + bias[n]; tile 64m x 128n, grid 256.
// Epilogue: LDS transpose -> out[b,e,t] = relu(C[b,t,e] * x[b,e,t]).
__global__ __launch_bounds__(256) void k_gemm_out(
    const unsigned short* __restrict__ Ahg, const unsigned short* __restrict__ Bhg,
    const float* __restrict__ bias, const float* __restrict__ x,
    float* __restrict__ out) {
  const int KD = 512;
  __shared__ __align__(16) union {
    struct {
      unsigned short Ah[64 * 32];
      unsigned short Bh[128 * 32];
    } st;                       // 12 KB staging
    float tile[64][129];        // 32.25 KB epilogue transpose
  } u;
  const int tid = threadIdx.x, lane = tid & 63, w = tid >> 6;
  // XCD swizzle: 32 blocks/XCD = 8m x 4n slab (A 0.5 MB + B 0.5 MB in L2)
  const int bid = blockIdx.x;
  const int xcd = bid & 7, j5 = bid >> 3;
  const int m0 = (xcd * 8 + (j5 >> 2)) * 64, n0 = (j5 & 3) * 128;
  const int wm = (w >> 1) * 32, wn = (w & 1) * 64;

  f32x4 acc[2][4];
#pragma unroll
  for (int i = 0; i < 2; i++)
#pragma unroll
    for (int j = 0; j < 4; j++) acc[i][j] = (f32x4){0.f, 0.f, 0.f, 0.f};

  const int srw = lane >> 2, sc = (lane & 3) * 8;
  const size_t b0 = (size_t)(n0 + w * 32 + srw) * KD + sc;
  const size_t b1 = b0 + (size_t)16 * KD;
  const size_t a0 = (size_t)(m0 + w * 16 + srw) * KD + sc;
  unsigned short* lB0 = &u.st.Bh[(w * 32) * 32];
  unsigned short* lB1 = &u.st.Bh[(w * 32 + 16) * 32];
  unsigned short* lAh0 = &u.st.Ah[(w * 16) * 32];

  const int fm = lane & 15, fq = (lane >> 4) * 8;

  for (int k0 = 0; k0 < KD; k0 += 32) {
    __syncthreads();
    GLL16(Ahg + a0 + k0, lAh0);
    GLL16(Bhg + b0 + k0, lB0);
    GLL16(Bhg + b1 + k0, lB1);
    __builtin_amdgcn_s_waitcnt(0);
    __syncthreads();

    bf16x8 ah[2], bh[4];
#pragma unroll
    for (int i = 0; i < 2; i++)
      ah[i] = *(const bf16x8*)&u.st.Ah[(wm + i * 16 + fm) * 32 + fq];
#pragma unroll
    for (int j = 0; j < 4; j++)
      bh[j] = *(const bf16x8*)&u.st.Bh[(wn + j * 16 + fm) * 32 + fq];
#pragma unroll
    for (int i = 0; i < 2; i++)
#pragma unroll
      for (int j = 0; j < 4; j++)
        acc[i][j] = MFMA(ah[i], bh[j], acc[i][j]);
  }

  __syncthreads();  // all frag reads done before tile overwrites staging
  // write acc+bias into transpose tile: tile[t_local][e_local]
  const int quad = lane >> 4;
#pragma unroll
  for (int i = 0; i < 2; i++)
#pragma unroll
    for (int j = 0; j < 4; j++) {
      int ln = wn + j * 16 + fm;
      float bv = bias[n0 + ln];
#pragma unroll
      for (int r = 0; r < 4; r++) {
        int lm = wm + i * 16 + quad * 4 + r;
        u.tile[lm][ln] = acc[i][j][r] + bv;
      }
    }
  __syncthreads();

  // out[b,e,t] = relu(tile[t][e] * x[b,e,t]); coalesced along t
  const int bb = m0 >> 11, t0 = m0 & 2047;
  const int tt = tid & 63, e0w = tid >> 6;
#pragma unroll
  for (int k = 0; k < 32; k++) {
    int ee = e0w + k * 4;
    size_t o = ((size_t)bb * 512 + n0 + ee) * 2048 + t0 + tt;
    float v = u.tile[tt][ee] * x[o];
    out[o] = fmaxf(v, 0.f);
  }
}

// ---------------------------------------------------------------------------
// K2: local attention. Block = (b,h, 64 queries). Window = 192 keys.
// V arrives already transposed in global [B,H,64,2048].
#define KSTR 88   // K_lds row stride (bf16): 176B, 2-way-free b128 reads
#define VSTR 216  // Vt/P row stride (bf16): 432B, 2-way-free b128 reads
__global__ __launch_bounds__(256) void k_attention(
    const unsigned short* __restrict__ Qs, const unsigned short* __restrict__ Kks,
    const unsigned short* __restrict__ VvT, unsigned short* __restrict__ ctx_hi) {
  __shared__ __align__(16) unsigned short KP_s[192 * KSTR];  // K, later P (64 x VSTR)
  __shared__ __align__(16) unsigned short Vt_s[64 * VSTR];   // V^T [dh][key]
  __shared__ float redm[4 * 64];
  __shared__ float reds[4 * 64];

  const int tid = threadIdx.x, lane = tid & 63, w = tid >> 6;
  const int q0 = blockIdx.x * 64;
  const int bh = blockIdx.y;
  const int j0 = q0 - 64;
  const size_t base = (size_t)bh * 2048 * 64;

  // stage K rows (clamped; garbage rows are masked before softmax)
  for (int idx = tid; idx < 192 * 8; idx += 256) {
    int r = idx >> 3, c = idx & 7;
    int j = j0 + r;
    j = j < 0 ? 0 : (j > 2047 ? 2047 : j);
    uint4 v = *(const uint4*)&Kks[base + (size_t)j * 64 + c * 8];
    *(uint4*)&KP_s[r * KSTR + c * 8] = v;
  }
  // stage V^T rows: pure uint4 copies (j0 and chunk starts 8-aligned -> a
  // chunk is never OOB-straddling; OOB chunks fully zero)
  for (int idx = tid; idx < 64 * 24; idx += 256) {
    int d = idx / 24, c8 = (idx % 24) * 8;
    int j = j0 + c8;
    uint4 v;
    if (j >= 0 && j < 2048)
      v = *(const uint4*)&VvT[base + (size_t)d * 2048 + j];
    else
      v = (uint4){0u, 0u, 0u, 0u};  // OOB keys ZERO (0*garbage hazard)
    *(uint4*)&Vt_s[d * VSTR + c8] = v;
  }

  // Q fragments straight from global (A layout: m=lane&15, k=quad*8+j)
  const int fm = lane & 15, quad = lane >> 4;
  bf16x8 aq[4][2];
#pragma unroll
  for (int mt = 0; mt < 4; mt++)
#pragma unroll
    for (int ks = 0; ks < 2; ks++)
      aq[mt][ks] = *(const bf16x8*)&Qs[base + (size_t)(q0 + mt * 16 + fm) * 64 +
                                       ks * 32 + quad * 8];
  __syncthreads();

  // S = Qs @ K^T ; wave covers key-cols [w*48, w*48+48)
  const int n0s = w * 48;
  f32x4 s_acc[4][3];
#pragma unroll
  for (int mt = 0; mt < 4; mt++)
#pragma unroll
    for (int nt = 0; nt < 3; nt++) s_acc[mt][nt] = (f32x4){0.f, 0.f, 0.f, 0.f};
#pragma unroll
  for (int nt = 0; nt < 3; nt++)
#pragma unroll
    for (int ks = 0; ks < 2; ks++) {
      bf16x8 bk =
          *(const bf16x8*)&KP_s[(n0s + nt * 16 + fm) * KSTR + ks * 32 + quad * 8];
#pragma unroll
      for (int mt = 0; mt < 4; mt++) s_acc[mt][nt] = MFMA(aq[mt][ks], bk, s_acc[mt][nt]);
    }

  // mask (REPLACE, not add) + per-row max
  float rm[4][4];
#pragma unroll
  for (int mt = 0; mt < 4; mt++)
#pragma unroll
    for (int r = 0; r < 4; r++) rm[mt][r] = -1e30f;
#pragma unroll
  for (int mt = 0; mt < 4; mt++)
#pragma unroll
    for (int nt = 0; nt < 3; nt++) {
      int jj = n0s + nt * 16 + fm;
      int jg = j0 + jj;
#pragma unroll
      for (int r = 0; r < 4; r++) {
        int ii = mt * 16 + quad * 4 + r;
        bool ok = (jj >= ii) && (jj <= ii + 128) && (jg >= 0) && (jg < 2048);
        float sv = ok ? s_acc[mt][nt][r] : -1e30f;
        s_acc[mt][nt][r] = sv;
        rm[mt][r] = fmaxf(rm[mt][r], sv);
      }
    }
  // reduce max over the 16-lane col group, then cross-wave via LDS
#pragma unroll
  for (int off = 1; off < 16; off <<= 1)
#pragma unroll
    for (int mt = 0; mt < 4; mt++)
#pragma unroll
      for (int r = 0; r < 4; r++)
        rm[mt][r] = fmaxf(rm[mt][r], __shfl_xor(rm[mt][r], off));
  if (fm == 0)
#pragma unroll
    for (int mt = 0; mt < 4; mt++)
#pragma unroll
      for (int r = 0; r < 4; r++)
        redm[w * 64 + mt * 16 + quad * 4 + r] = rm[mt][r];
  __syncthreads();
  float fmx[4][4];
#pragma unroll
  for (int mt = 0; mt < 4; mt++)
#pragma unroll
    for (int r = 0; r < 4; r++) {
      int row = mt * 16 + quad * 4 + r;
      fmx[mt][r] = fmaxf(fmaxf(redm[row], redm[64 + row]),
                         fmaxf(redm[128 + row], redm[192 + row]));
    }
  // exp + row sum (masked entries underflow to exactly 0)
  float rs[4][4];
#pragma unroll
  for (int mt = 0; mt < 4; mt++)
#pragma unroll
    for (int r = 0; r < 4; r++) rs[mt][r] = 0.f;
#pragma unroll
  for (int mt = 0; mt < 4; mt++)
#pragma unroll
    for (int nt = 0; nt < 3; nt++)
#pragma unroll
      for (int r = 0; r < 4; r++) {
        float e = __expf(s_acc[mt][nt][r] - fmx[mt][r]);
        s_acc[mt][nt][r] = e;
        rs[mt][r] += e;
      }
#pragma unroll
  for (int off = 1; off < 16; off <<= 1)
#pragma unroll
    for (int mt = 0; mt < 4; mt++)
#pragma unroll
      for (int r = 0; r < 4; r++) rs[mt][r] += __shfl_xor(rs[mt][r], off);
  if (fm == 0)
#pragma unroll
    for (int mt = 0; mt < 4; mt++)
#pragma unroll
      for (int r = 0; r < 4; r++)
        reds[w * 64 + mt * 16 + quad * 4 + r] = rs[mt][r];
  __syncthreads();  // also guarantees all K_lds reads done before P overwrites
  float inv[4][4];
#pragma unroll
  for (int mt = 0; mt < 4; mt++)
#pragma unroll
    for (int r = 0; r < 4; r++) {
      int row = mt * 16 + quad * 4 + r;
      inv[mt][r] =
          1.0f / (reds[row] + reds[64 + row] + reds[128 + row] + reds[192 + row]);
    }
  // write P (bf16) into KP_s region with stride VSTR (C layout -> memory)
#pragma unroll
  for (int mt = 0; mt < 4; mt++)
#pragma unroll
    for (int nt = 0; nt < 3; nt++) {
      int col = n0s + nt * 16 + fm;
#pragma unroll
      for (int r = 0; r < 4; r++) {
        int row = mt * 16 + quad * 4 + r;
        KP_s[row * VSTR + col] = f2bf(s_acc[mt][nt][r] * inv[mt][r]);
      }
    }
  __syncthreads();

  // ctx = P @ V ; wave covers dh-cols [w*16, w*16+16)
  const int n0v = w * 16;
  f32x4 o_acc[4];
#pragma unroll
  for (int mt = 0; mt < 4; mt++) o_acc[mt] = (f32x4){0.f, 0.f, 0.f, 0.f};
#pragma unroll
  for (int ks = 0; ks < 6; ks++) {
    bf16x8 bv = *(const bf16x8*)&Vt_s[(n0v + fm) * VSTR + ks * 32 + quad * 8];
#pragma unroll
    for (int mt = 0; mt < 4; mt++) {
      bf16x8 ap = *(const bf16x8*)&KP_s[(mt * 16 + fm) * VSTR + ks * 32 + quad * 8];
      o_acc[mt] = MFMA(ap, bv, o_acc[mt]);
    }
  }
  // write ctx bf16 [B*T, 512]
  const int bb = bh >> 3, h = bh & 7;
#pragma unroll
  for (int mt = 0; mt < 4; mt++)
#pragma unroll
    for (int r = 0; r < 4; r++) {
      int t = q0 + mt * 16 + quad * 4 + r;
      int c = h * 64 + n0v + fm;
      ctx_hi[((size_t)(bb * 2048 + t)) * 512 + c] = f2bf(o_acc[mt][r]);
    }
}

// ---------------------------------------------------------------------------
extern "C" void kernel_launch(void* const* d_in, const int* in_sizes, int n_in,
                              void* d_out, int out_size, void* d_ws, size_t ws_size,
                              hipStream_t stream) {
  const float* x = (const float*)d_in[0];
  const float* w_in = (const float*)d_in[1];
  const float* b_in = (const float*)d_in[2];
  const float* w_out = (const float*)d_in[3];
  const float* b_out = (const float*)d_in[4];
  float* out = (float*)d_out;

  uint8_t* ws = (uint8_t*)d_ws;
  unsigned short* xT_hi = (unsigned short*)(ws + 0);           // 4 MiB
  unsigned short* wih   = (unsigned short*)(ws + 8388608);     // 1.5 MiB
  unsigned short* woh   = (unsigned short*)(ws + 9961472);     // 0.5 MiB
  unsigned short* Qs    = (unsigned short*)(ws + 12582912);    // 4 MiB
  unsigned short* Kk    = (unsigned short*)(ws + 16777216);    // 4 MiB
  unsigned short* VvT   = (unsigned short*)(ws + 20971520);    // 4 MiB [B,H,64,T]
  unsigned short* ctxh  = (unsigned short*)(ws + 25165824);    // 4 MiB

  k_prep<<<dim3(64, 17, 2), 256, 0, stream>>>(x, w_in, w_out, xT_hi, wih, woh);
  k_gemm_qkv<<<384, 256, 0, stream>>>(xT_hi, wih, b_in, Qs, Kk, VvT);
  k_attention<<<dim3(32, 16), 256, 0, stream>>>(Qs, Kk, VvT, ctxh);
  k_gemm_out<<<256, 256, 0, stream>>>(ctxh, woh, b_out, x, out);
}